// Round 1
// baseline (372.061 us; speedup 1.0000x reference)
//
#include <hip/hip_runtime.h>
#include <stdint.h>

#define T_SEQ 2048
#define D_MODEL 1024
#define NH 16
#define DH 64
#define NROWS 4096  // B*T

typedef __bf16 bf16x8 __attribute__((ext_vector_type(8)));
typedef float floatx4 __attribute__((ext_vector_type(4)));

static __device__ __forceinline__ unsigned short f32_bf16(float f) {
    union { float f; unsigned int u; } c; c.f = f;
    unsigned int u = c.u;
    u = u + 0x7FFFu + ((u >> 16) & 1u);   // RNE
    return (unsigned short)(u >> 16);
}

static __device__ __forceinline__ unsigned int pack2_bf16(float a, float b) {
    return (unsigned int)f32_bf16(a) | ((unsigned int)f32_bf16(b) << 16);
}

static __device__ __forceinline__ floatx4 mfma16(bf16x8 a, bf16x8 b, floatx4 c) {
    return __builtin_amdgcn_mfma_f32_16x16x32_bf16(a, b, c, 0, 0, 0);
}

// ---------------- conversion kernels ----------------

// x fp32 -> bf16, flat
__global__ __launch_bounds__(256) void k_conv_x(const float* __restrict__ src,
                                                unsigned short* __restrict__ dst) {
    int i = (blockIdx.x * 256 + threadIdx.x) * 4;
    float4 v = *(const float4*)(src + i);
    uint2 o;
    o.x = pack2_bf16(v.x, v.y);
    o.y = pack2_bf16(v.z, v.w);
    *(uint2*)(dst + i) = o;
}

// W row-permuted: dst row n' = h*64+d  <=  src row f = d*16+h = (n'&63)*16 + (n'>>6)
__global__ __launch_bounds__(256) void k_conv_wperm_row(const float* __restrict__ src,
                                                        unsigned short* __restrict__ dst) {
    int np = blockIdx.x;
    int f = (np & 63) * 16 + (np >> 6);
    int c = threadIdx.x * 4;
    float4 v = *(const float4*)(src + (long)f * D_MODEL + c);
    uint2 o;
    o.x = pack2_bf16(v.x, v.y);
    o.y = pack2_bf16(v.z, v.w);
    *(uint2*)(dst + (long)np * D_MODEL + c) = o;
}

// Wo column-permuted: dst[n][f'] = src[n][(f'&63)*16 + (f'>>6)]
__global__ __launch_bounds__(256) void k_conv_wo(const float* __restrict__ src,
                                                 unsigned short* __restrict__ dst) {
    int n = blockIdx.x;
    int fp = threadIdx.x * 4;
    const float* row = src + (long)n * D_MODEL;
    unsigned short o[4];
    #pragma unroll
    for (int k = 0; k < 4; k++) {
        int f = fp + k;
        o[k] = f32_bf16(row[(f & 63) * 16 + (f >> 6)]);
    }
    *(uint2*)(dst + (long)n * D_MODEL + fp) = *(const uint2*)o;
}

// ---------------- GEMM: C = A(bf16) @ W(bf16)^T, K = 1024 ----------------
// BM=128, BN=64, BK=64. 256 threads = 4 waves in 2x2; wave tile 64x32.
// MODE 0: Q -> q_ws[(b*16+h)*T + i][d] = (acc + bq[f]) * 0.125
// MODE 1: K -> k_ws same layout
// MODE 2: V -> v_ws same layout
// MODE 3: out = acc + bo[n] + resid -> fp32 [row][n]
template <int MODE>
__global__ __launch_bounds__(256) void k_gemm(const unsigned short* __restrict__ A,
                                              const unsigned short* __restrict__ W,
                                              const float* __restrict__ bias,
                                              const float* __restrict__ resid,
                                              unsigned short* __restrict__ out_bf,
                                              float* __restrict__ out_f32) {
    __shared__ unsigned short lds_a[128 * 64];
    __shared__ unsigned short lds_b[64 * 64];
    const int tid = threadIdx.x;
    const int w = tid >> 6, l = tid & 63;
    const int lrow = l & 15, lq = l >> 4;
    const int wm = (w >> 1) * 64, wn = (w & 1) * 32;
    const long am0 = (long)blockIdx.x * 128;
    const long wn0 = (long)blockIdx.y * 64;

    floatx4 acc[4][2] = {};
    const int sr = tid >> 3, sc = (tid & 7) << 3;

    for (int k0 = 0; k0 < D_MODEL; k0 += 64) {
        #pragma unroll
        for (int p = 0; p < 4; p++)
            *(uint4*)(lds_a + (sr + p * 32) * 64 + sc) =
                *(const uint4*)(A + (am0 + sr + p * 32) * D_MODEL + k0 + sc);
        #pragma unroll
        for (int p = 0; p < 2; p++)
            *(uint4*)(lds_b + (sr + p * 32) * 64 + sc) =
                *(const uint4*)(W + (wn0 + sr + p * 32) * D_MODEL + k0 + sc);
        __syncthreads();

        bf16x8 af[4][2], bf[2][2];
        #pragma unroll
        for (int mt = 0; mt < 4; mt++)
            #pragma unroll
            for (int ks = 0; ks < 2; ks++)
                af[mt][ks] = *(const bf16x8*)(lds_a + (wm + mt * 16 + lrow) * 64 + ks * 32 + lq * 8);
        #pragma unroll
        for (int nt = 0; nt < 2; nt++)
            #pragma unroll
            for (int ks = 0; ks < 2; ks++)
                bf[nt][ks] = *(const bf16x8*)(lds_b + (wn + nt * 16 + lrow) * 64 + ks * 32 + lq * 8);
        #pragma unroll
        for (int mt = 0; mt < 4; mt++)
            #pragma unroll
            for (int nt = 0; nt < 2; nt++)
                #pragma unroll
                for (int ks = 0; ks < 2; ks++)
                    acc[mt][nt] = mfma16(af[mt][ks], bf[nt][ks], acc[mt][nt]);
        __syncthreads();
    }

    // epilogue
    #pragma unroll
    for (int mt = 0; mt < 4; mt++) {
        #pragma unroll
        for (int nt = 0; nt < 2; nt++) {
            int n = (int)wn0 + wn + nt * 16 + lrow;      // permuted col n'=h*64+d (modes 0-2)
            #pragma unroll
            for (int r = 0; r < 4; r++) {
                int row = (int)am0 + wm + mt * 16 + lq * 4 + r;
                float v = acc[mt][nt][r];
                if (MODE <= 2) {
                    int h = n >> 6, d = n & 63;
                    v += bias[d * 16 + h];               // original bias index f = d*16+h
                    if (MODE == 0) v *= 0.125f;          // 1/sqrt(Dh)
                    int b = row >> 11, i = row & 2047;
                    long idx = ((long)(b * 16 + h) * T_SEQ + i) * DH + d;
                    out_bf[idx] = f32_bf16(v);
                } else {
                    long idx = (long)row * D_MODEL + n;
                    out_f32[idx] = v + bias[n] + resid[idx];
                }
            }
        }
    }
}

// ---------------- V transpose per head: v[bh][j][d] -> vt[bh][d][j] ----------------
__global__ __launch_bounds__(256) void k_vtrans(const unsigned short* __restrict__ v_ws,
                                                unsigned short* __restrict__ vt_ws) {
    __shared__ unsigned short tl[64][80];  // padded
    int bh = blockIdx.y, j0 = blockIdx.x * 64;
    int t = threadIdx.x;
    {
        int j = t >> 2, dg = (t & 3) * 16;
        const unsigned short* src = v_ws + ((long)bh * T_SEQ + j0 + j) * DH + dg;
        unsigned short tmp[16];
        *(uint4*)tmp = *(const uint4*)src;
        *(uint4*)(tmp + 8) = *(const uint4*)(src + 8);
        #pragma unroll
        for (int m = 0; m < 16; m++) tl[dg + m][j] = tmp[m];
    }
    __syncthreads();
    {
        int d = t >> 2, jg = (t & 3) * 16;
        unsigned short o[16];
        #pragma unroll
        for (int m = 0; m < 16; m++) o[m] = tl[d][jg + m];
        unsigned short* dst = vt_ws + ((long)bh * DH + d) * T_SEQ + j0 + jg;
        *(uint4*)dst = *(const uint4*)o;
        *(uint4*)(dst + 8) = *(const uint4*)(o + 8);
    }
}

// ---------------- attention: flash-style, 64 q-rows/block, j-tiles of 64 ----------------
__global__ __launch_bounds__(256) void k_attn(const unsigned short* __restrict__ q_ws,
                                              const unsigned short* __restrict__ k_ws,
                                              const unsigned short* __restrict__ vt_ws,
                                              unsigned short* __restrict__ att) {
    __shared__ unsigned short lds_k[64 * 64];
    __shared__ unsigned short lds_v[64 * 64];
    __shared__ unsigned short p_lds[4][16 * 64];
    const int tid = threadIdx.x;
    const int w = tid >> 6, l = tid & 63;
    const int lrow = l & 15, lq = l >> 4;
    const int bh = blockIdx.y;
    const int i0 = blockIdx.x * 64;
    const unsigned short* qh = q_ws + (long)bh * T_SEQ * DH;
    const unsigned short* kh = k_ws + (long)bh * T_SEQ * DH;
    const unsigned short* vth = vt_ws + (long)bh * DH * T_SEQ;

    bf16x8 qf[2];
    {
        const unsigned short* qp = qh + (long)(i0 + w * 16 + lrow) * DH + lq * 8;
        qf[0] = *(const bf16x8*)qp;
        qf[1] = *(const bf16x8*)(qp + 32);
    }
    float m_run[4], l_run[4];
    floatx4 o_acc[4] = {};
    #pragma unroll
    for (int r = 0; r < 4; r++) { m_run[r] = -1e30f; l_run[r] = 0.0f; }

    const int sr = tid >> 3, sc = (tid & 7) << 3;
    for (int jt = 0; jt < T_SEQ / 64; jt++) {
        int j0 = jt * 64;
        __syncthreads();
        #pragma unroll
        for (int p = 0; p < 2; p++) {
            *(uint4*)(lds_k + (sr + p * 32) * 64 + sc) =
                *(const uint4*)(kh + (long)(j0 + sr + p * 32) * DH + sc);
            *(uint4*)(lds_v + (sr + p * 32) * 64 + sc) =
                *(const uint4*)(vth + (long)(sr + p * 32) * T_SEQ + j0 + sc);
        }
        __syncthreads();

        // S tile: rows (this wave's 16 q rows), cols = 64 j's
        floatx4 s[4] = {};
        #pragma unroll
        for (int nt = 0; nt < 4; nt++) {
            const unsigned short* kp = lds_k + (nt * 16 + lrow) * 64 + lq * 8;
            s[nt] = mfma16(qf[0], *(const bf16x8*)kp, s[nt]);
            s[nt] = mfma16(qf[1], *(const bf16x8*)(kp + 32), s[nt]);
        }
        // online softmax; C-layout: row = lq*4+r, col = nt*16+lrow
        #pragma unroll
        for (int r = 0; r < 4; r++) {
            float mx = fmaxf(fmaxf(s[0][r], s[1][r]), fmaxf(s[2][r], s[3][r]));
            mx = fmaxf(mx, __shfl_xor(mx, 1));
            mx = fmaxf(mx, __shfl_xor(mx, 2));
            mx = fmaxf(mx, __shfl_xor(mx, 4));
            mx = fmaxf(mx, __shfl_xor(mx, 8));
            float mnew = fmaxf(m_run[r], mx);
            float alpha = __expf(m_run[r] - mnew);
            m_run[r] = mnew;
            float rs = 0.0f;
            #pragma unroll
            for (int nt = 0; nt < 4; nt++) {
                float p = __expf(s[nt][r] - mnew);
                s[nt][r] = p;
                rs += p;
            }
            rs += __shfl_xor(rs, 1);
            rs += __shfl_xor(rs, 2);
            rs += __shfl_xor(rs, 4);
            rs += __shfl_xor(rs, 8);
            l_run[r] = l_run[r] * alpha + rs;
            #pragma unroll
            for (int dt = 0; dt < 4; dt++) o_acc[dt][r] *= alpha;
        }
        // P: C-layout -> A-layout via per-wave LDS roundtrip
        unsigned short* pw = &p_lds[w][0];
        #pragma unroll
        for (int nt = 0; nt < 4; nt++)
            #pragma unroll
            for (int r = 0; r < 4; r++)
                pw[(lq * 4 + r) * 64 + nt * 16 + lrow] = f32_bf16(s[nt][r]);
        bf16x8 pf0 = *(const bf16x8*)(pw + lrow * 64 + lq * 8);
        bf16x8 pf1 = *(const bf16x8*)(pw + lrow * 64 + 32 + lq * 8);
        #pragma unroll
        for (int dt = 0; dt < 4; dt++) {
            const unsigned short* vp = lds_v + (dt * 16 + lrow) * 64 + lq * 8;
            o_acc[dt] = mfma16(pf0, *(const bf16x8*)vp, o_acc[dt]);
            o_acc[dt] = mfma16(pf1, *(const bf16x8*)(vp + 32), o_acc[dt]);
        }
    }
    // finalize: att[b*T+i][h*64+d] (head-contiguous permuted features)
    int h = bh & 15, b = bh >> 4;
    #pragma unroll
    for (int dt = 0; dt < 4; dt++)
        #pragma unroll
        for (int r = 0; r < 4; r++) {
            int i = i0 + w * 16 + lq * 4 + r;
            int d = dt * 16 + lrow;
            float v = o_acc[dt][r] / l_run[r];
            att[((long)(b * T_SEQ + i)) * D_MODEL + h * 64 + d] = f32_bf16(v);
        }
}

// ---------------- LayerNorm in-place on d_out ----------------
__global__ __launch_bounds__(256) void k_ln(float* __restrict__ io,
                                            const float* __restrict__ gamma,
                                            const float* __restrict__ beta) {
    int row = blockIdx.x, t = threadIdx.x;
    float* p = io + (long)row * D_MODEL + t * 4;
    float4 v = *(float4*)p;
    float s = v.x + v.y + v.z + v.w;
    float ss = v.x * v.x + v.y * v.y + v.z * v.z + v.w * v.w;
    #pragma unroll
    for (int m = 1; m < 64; m <<= 1) {
        s += __shfl_xor(s, m);
        ss += __shfl_xor(ss, m);
    }
    __shared__ float red[8];
    if ((t & 63) == 0) { red[t >> 6] = s; red[4 + (t >> 6)] = ss; }
    __syncthreads();
    s = red[0] + red[1] + red[2] + red[3];
    ss = red[4] + red[5] + red[6] + red[7];
    float mu = s * (1.0f / 1024.0f);
    float var = ss * (1.0f / 1024.0f) - mu * mu;
    float rstd = rsqrtf(var + 1e-5f);
    float4 g = *(const float4*)(gamma + t * 4);
    float4 be = *(const float4*)(beta + t * 4);
    float4 o;
    o.x = (v.x - mu) * rstd * g.x + be.x;
    o.y = (v.y - mu) * rstd * g.y + be.y;
    o.z = (v.z - mu) * rstd * g.z + be.z;
    o.w = (v.w - mu) * rstd * g.w + be.w;
    *(float4*)p = o;
}

extern "C" void kernel_launch(void* const* d_in, const int* in_sizes, int n_in,
                              void* d_out, int out_size, void* d_ws, size_t ws_size,
                              hipStream_t stream) {
    const float* x = (const float*)d_in[0];
    const float* Wq = (const float*)d_in[1];
    const float* bq = (const float*)d_in[2];
    const float* Wk = (const float*)d_in[3];
    const float* bk = (const float*)d_in[4];
    const float* Wv = (const float*)d_in[5];
    const float* bv = (const float*)d_in[6];
    const float* Wo = (const float*)d_in[7];
    const float* bo = (const float*)d_in[8];
    const float* gamma = (const float*)d_in[9];
    const float* beta = (const float*)d_in[10];
    float* out = (float*)d_out;

    char* ws = (char*)d_ws;
    unsigned short* x_bf = (unsigned short*)(ws);                       // 8 MB (reused as att)
    unsigned short* wq_bf = (unsigned short*)(ws + ((size_t)8 << 20));  // 2 MB
    unsigned short* wk_bf = (unsigned short*)(ws + ((size_t)10 << 20));
    unsigned short* wv_bf = (unsigned short*)(ws + ((size_t)12 << 20));
    unsigned short* wo_bf = (unsigned short*)(ws + ((size_t)14 << 20));
    unsigned short* q_ws = (unsigned short*)(ws + ((size_t)16 << 20));  // 8 MB
    unsigned short* k_ws = (unsigned short*)(ws + ((size_t)24 << 20));  // 8 MB
    unsigned short* v_ws = (unsigned short*)(ws + ((size_t)32 << 20));  // 8 MB
    unsigned short* vt_ws = (unsigned short*)(ws + ((size_t)40 << 20)); // 8 MB
    unsigned short* att = x_bf;  // alias: x_bf dead after QKV GEMMs

    k_conv_x<<<NROWS * D_MODEL / 1024, 256, 0, stream>>>(x, x_bf);
    k_conv_wperm_row<<<1024, 256, 0, stream>>>(Wq, wq_bf);
    k_conv_wperm_row<<<1024, 256, 0, stream>>>(Wk, wk_bf);
    k_conv_wperm_row<<<1024, 256, 0, stream>>>(Wv, wv_bf);
    k_conv_wo<<<1024, 256, 0, stream>>>(Wo, wo_bf);

    dim3 gg(NROWS / 128, D_MODEL / 64);
    k_gemm<0><<<gg, 256, 0, stream>>>(x_bf, wq_bf, bq, nullptr, q_ws, nullptr);
    k_gemm<1><<<gg, 256, 0, stream>>>(x_bf, wk_bf, bk, nullptr, k_ws, nullptr);
    k_gemm<2><<<gg, 256, 0, stream>>>(x_bf, wv_bf, bv, nullptr, v_ws, nullptr);

    k_vtrans<<<dim3(T_SEQ / 64, 32), 256, 0, stream>>>(v_ws, vt_ws);
    k_attn<<<dim3(T_SEQ / 64, 32), 256, 0, stream>>>(q_ws, k_ws, vt_ws, att);

    k_gemm<3><<<gg, 256, 0, stream>>>(att, wo_bf, bo, x, nullptr, out);
    k_ln<<<NROWS, 256, 0, stream>>>(out, gamma, beta);
}

// Round 2
// 263.649 us; speedup vs baseline: 1.4112x; 1.4112x over previous
//
#include <hip/hip_runtime.h>
#include <stdint.h>

#define T_SEQ 2048
#define D_MODEL 1024
#define NH 16
#define DH 64
#define NROWS 4096  // B*T

typedef __bf16 bf16x8 __attribute__((ext_vector_type(8)));
typedef float floatx4 __attribute__((ext_vector_type(4)));

#define AS1 __attribute__((address_space(1)))
#define AS3 __attribute__((address_space(3)))

static __device__ __forceinline__ void gl2lds16(const unsigned short* g, unsigned short* s) {
    __builtin_amdgcn_global_load_lds((const AS1 unsigned int*)g, (AS3 unsigned int*)s, 16, 0, 0);
}

static __device__ __forceinline__ unsigned short f32_bf16(float f) {
    union { float f; unsigned int u; } c; c.f = f;
    unsigned int u = c.u;
    u = u + 0x7FFFu + ((u >> 16) & 1u);   // RNE
    return (unsigned short)(u >> 16);
}

static __device__ __forceinline__ unsigned int pack2_bf16(float a, float b) {
    return (unsigned int)f32_bf16(a) | ((unsigned int)f32_bf16(b) << 16);
}

static __device__ __forceinline__ floatx4 mfma16(bf16x8 a, bf16x8 b, floatx4 c) {
    return __builtin_amdgcn_mfma_f32_16x16x32_bf16(a, b, c, 0, 0, 0);
}

#define QSCALE 0.1803368801111204f   // (1/8) * log2(e); softmax done in exp2 domain
#define EXP2_SHIFT 10.0f

// ---------------- conversion kernels ----------------

__global__ __launch_bounds__(256) void k_conv_x(const float* __restrict__ src,
                                                unsigned short* __restrict__ dst) {
    int i = (blockIdx.x * 256 + threadIdx.x) * 4;
    float4 v = *(const float4*)(src + i);
    uint2 o;
    o.x = pack2_bf16(v.x, v.y);
    o.y = pack2_bf16(v.z, v.w);
    *(uint2*)(dst + i) = o;
}

// W row-permuted: dst row n' = h*64+d  <=  src row f = d*16+h = (n'&63)*16 + (n'>>6)
__global__ __launch_bounds__(256) void k_conv_wperm_row(const float* __restrict__ src,
                                                        unsigned short* __restrict__ dst) {
    int np = blockIdx.x;
    int f = (np & 63) * 16 + (np >> 6);
    int c = threadIdx.x * 4;
    float4 v = *(const float4*)(src + (long)f * D_MODEL + c);
    uint2 o;
    o.x = pack2_bf16(v.x, v.y);
    o.y = pack2_bf16(v.z, v.w);
    *(uint2*)(dst + (long)np * D_MODEL + c) = o;
}

// Wo column-permuted: dst[n][f'] = src[n][(f'&63)*16 + (f'>>6)]
__global__ __launch_bounds__(256) void k_conv_wo(const float* __restrict__ src,
                                                 unsigned short* __restrict__ dst) {
    int n = blockIdx.x;
    int fp = threadIdx.x * 4;
    const float* row = src + (long)n * D_MODEL;
    unsigned short o[4];
    #pragma unroll
    for (int k = 0; k < 4; k++) {
        int f = fp + k;
        o[k] = f32_bf16(row[(f & 63) * 16 + (f >> 6)]);
    }
    *(uint2*)(dst + (long)n * D_MODEL + fp) = *(const uint2*)o;
}

// ---------------- GEMM: C = A(bf16) @ W(bf16)^T, K = 1024, m97-style ----------------
// BM=128, BK=64, 256 threads = 4 waves in 2x2; wave tile 64 x (BN/2).
// MODE 0: fused QKV (W is stacked 3072x1024; blockIdx.y>>3 selects tensor); out head-layout bf16
// MODE 1: O-projection; out = acc + bo[n] + resid -> fp32 [row][n]
template <int BN, int MODE>
__global__ __launch_bounds__(256) void k_gemm(const unsigned short* __restrict__ A,
                                              const unsigned short* __restrict__ W,
                                              const float* __restrict__ b0,
                                              const float* __restrict__ b1,
                                              const float* __restrict__ b2,
                                              const float* __restrict__ resid,
                                              unsigned short* __restrict__ out_bf,
                                              float* __restrict__ out_f32) {
    constexpr int NT = BN / 32;          // n-frags per wave
    constexpr int NCB = BN / 32;         // B chunks (1KB) per wave
    __shared__ unsigned short lds_a[128 * 64];
    __shared__ unsigned short lds_b[BN * 64];
    const int tid = threadIdx.x;
    const int w = tid >> 6, l = tid & 63;
    const int lrow = l & 15, lq = l >> 4;
    const int wm = (w >> 1) * 64, wn = (w & 1) * (BN / 2);
    const long am0 = (long)blockIdx.x * 128;
    const long wn0 = (long)blockIdx.y * BN;

    floatx4 acc[4][NT] = {};
    const int grow = l >> 3, gcol = (l & 7) * 8;   // within a 1KB chunk: 8 rows x 128B

    for (int k0 = 0; k0 < D_MODEL; k0 += 64) {
        #pragma unroll
        for (int c = 0; c < 4; c++) {
            int chunk = w * 4 + c;                  // 16 chunks cover 128 rows
            gl2lds16(A + (am0 + chunk * 8 + grow) * D_MODEL + k0 + gcol,
                     lds_a + chunk * 512);
        }
        #pragma unroll
        for (int c = 0; c < NCB; c++) {
            int chunk = w * NCB + c;                // BN/8 chunks cover BN rows
            gl2lds16(W + (wn0 + chunk * 8 + grow) * D_MODEL + k0 + gcol,
                     lds_b + chunk * 512);
        }
        __syncthreads();

        bf16x8 af[4][2], bf[NT][2];
        #pragma unroll
        for (int mt = 0; mt < 4; mt++)
            #pragma unroll
            for (int ks = 0; ks < 2; ks++)
                af[mt][ks] = *(const bf16x8*)(lds_a + (wm + mt * 16 + lrow) * 64 + ks * 32 + lq * 8);
        #pragma unroll
        for (int nt = 0; nt < NT; nt++)
            #pragma unroll
            for (int ks = 0; ks < 2; ks++)
                bf[nt][ks] = *(const bf16x8*)(lds_b + (wn + nt * 16 + lrow) * 64 + ks * 32 + lq * 8);
        #pragma unroll
        for (int mt = 0; mt < 4; mt++)
            #pragma unroll
            for (int nt = 0; nt < NT; nt++)
                #pragma unroll
                for (int ks = 0; ks < 2; ks++)
                    acc[mt][nt] = mfma16(af[mt][ks], bf[nt][ks], acc[mt][nt]);
        __syncthreads();
    }

    // epilogue
    if (MODE == 0) {
        int tensor = blockIdx.y >> 3;                    // 0=Q 1=K 2=V
        int nbase = (blockIdx.y & 7) * 128;
        const float* bias = tensor == 0 ? b0 : tensor == 1 ? b1 : b2;
        float scale = tensor == 0 ? QSCALE : 1.0f;
        unsigned short* outt = out_bf + (size_t)tensor * (32u * T_SEQ * DH);
        #pragma unroll
        for (int mt = 0; mt < 4; mt++) {
            #pragma unroll
            for (int nt = 0; nt < NT; nt++) {
                int n = nbase + wn + nt * 16 + lrow;     // n' = h*64+d
                int h = n >> 6, d = n & 63;
                float bb = bias[d * 16 + h];
                #pragma unroll
                for (int r = 0; r < 4; r++) {
                    int row = (int)am0 + wm + mt * 16 + lq * 4 + r;
                    float v = (acc[mt][nt][r] + bb) * scale;
                    int b = row >> 11, i = row & 2047;
                    long idx = ((long)(b * 16 + h) * T_SEQ + i) * DH + d;
                    outt[idx] = f32_bf16(v);
                }
            }
        }
    } else {
        #pragma unroll
        for (int mt = 0; mt < 4; mt++) {
            #pragma unroll
            for (int nt = 0; nt < NT; nt++) {
                int n = (int)wn0 + wn + nt * 16 + lrow;
                float bb = b0[n];
                #pragma unroll
                for (int r = 0; r < 4; r++) {
                    int row = (int)am0 + wm + mt * 16 + lq * 4 + r;
                    long idx = (long)row * D_MODEL + n;
                    out_f32[idx] = acc[mt][nt][r] + bb + resid[idx];
                }
            }
        }
    }
}

// ---------------- V transpose per head: v[bh][j][d] -> vt[bh][d][j] ----------------
__global__ __launch_bounds__(256) void k_vtrans(const unsigned short* __restrict__ v_ws,
                                                unsigned short* __restrict__ vt_ws) {
    __shared__ unsigned short tl[64][80];  // padded
    int bh = blockIdx.y, j0 = blockIdx.x * 64;
    int t = threadIdx.x;
    {
        int j = t >> 2, dg = (t & 3) * 16;
        const unsigned short* src = v_ws + ((long)bh * T_SEQ + j0 + j) * DH + dg;
        unsigned short tmp[16];
        *(uint4*)tmp = *(const uint4*)src;
        *(uint4*)(tmp + 8) = *(const uint4*)(src + 8);
        #pragma unroll
        for (int m = 0; m < 16; m++) tl[dg + m][j] = tmp[m];
    }
    __syncthreads();
    {
        int d = t >> 2, jg = (t & 3) * 16;
        unsigned short o[16];
        #pragma unroll
        for (int m = 0; m < 16; m++) o[m] = tl[d][jg + m];
        unsigned short* dst = vt_ws + ((long)bh * DH + d) * T_SEQ + j0 + jg;
        *(uint4*)dst = *(const uint4*)o;
        *(uint4*)(dst + 8) = *(const uint4*)(o + 8);
    }
}

// ---------------- attention: flash-lite (no running max; exp2 domain) ----------------
// Q pre-scaled by (1/8)*log2e. p = exp2(s - 10); constant shift cancels in o/l.
#define PAD 72   // 144B row stride: 16B-aligned, <=2-way bank aliasing
__global__ __launch_bounds__(256) void k_attn(const unsigned short* __restrict__ q_ws,
                                              const unsigned short* __restrict__ k_ws,
                                              const unsigned short* __restrict__ vt_ws,
                                              unsigned short* __restrict__ att) {
    __shared__ unsigned short lds_k[64 * PAD];
    __shared__ unsigned short lds_v[64 * PAD];
    __shared__ unsigned short p_lds[4][16 * PAD];
    const int tid = threadIdx.x;
    const int w = tid >> 6, l = tid & 63;
    const int lrow = l & 15, lq = l >> 4;
    const int bh = blockIdx.y;
    const int i0 = blockIdx.x * 64;
    const unsigned short* kh = k_ws + (long)bh * T_SEQ * DH;
    const unsigned short* vth = vt_ws + (long)bh * DH * T_SEQ;

    bf16x8 qf[2];
    {
        const unsigned short* qp = q_ws + ((long)bh * T_SEQ + i0 + w * 16 + lrow) * DH + lq * 8;
        qf[0] = *(const bf16x8*)qp;
        qf[1] = *(const bf16x8*)(qp + 32);
    }
    float l_run[4] = {0.f, 0.f, 0.f, 0.f};
    floatx4 o_acc[4] = {};

    const int srow = tid >> 3, scol = (tid & 7) * 8;
    for (int jt = 0; jt < T_SEQ / 64; jt++) {
        int j0 = jt * 64;
        __syncthreads();
        *(uint4*)(lds_k + srow * PAD + scol) = *(const uint4*)(kh + (long)(j0 + srow) * DH + scol);
        *(uint4*)(lds_k + (srow + 32) * PAD + scol) = *(const uint4*)(kh + (long)(j0 + srow + 32) * DH + scol);
        *(uint4*)(lds_v + srow * PAD + scol) = *(const uint4*)(vth + (long)srow * T_SEQ + j0 + scol);
        *(uint4*)(lds_v + (srow + 32) * PAD + scol) = *(const uint4*)(vth + (long)(srow + 32) * T_SEQ + j0 + scol);
        __syncthreads();

        floatx4 s[4] = {};
        #pragma unroll
        for (int nt = 0; nt < 4; nt++) {
            const unsigned short* kp = lds_k + (nt * 16 + lrow) * PAD + lq * 8;
            s[nt] = mfma16(qf[0], *(const bf16x8*)kp, s[nt]);
            s[nt] = mfma16(qf[1], *(const bf16x8*)(kp + 32), s[nt]);
        }
        // p = exp2(s - 10); accumulate per-lane row-sum partials; P -> bf16 (truncate) -> LDS
        unsigned short* pw = &p_lds[w][0];
        #pragma unroll
        for (int r = 0; r < 4; r++) {
            float p0 = __builtin_amdgcn_exp2f(s[0][r] - EXP2_SHIFT);
            float p1 = __builtin_amdgcn_exp2f(s[1][r] - EXP2_SHIFT);
            float p2 = __builtin_amdgcn_exp2f(s[2][r] - EXP2_SHIFT);
            float p3 = __builtin_amdgcn_exp2f(s[3][r] - EXP2_SHIFT);
            l_run[r] += (p0 + p1) + (p2 + p3);
            int rowoff = (lq * 4 + r) * PAD + lrow;
            pw[rowoff]      = (unsigned short)(__float_as_uint(p0) >> 16);
            pw[rowoff + 16] = (unsigned short)(__float_as_uint(p1) >> 16);
            pw[rowoff + 32] = (unsigned short)(__float_as_uint(p2) >> 16);
            pw[rowoff + 48] = (unsigned short)(__float_as_uint(p3) >> 16);
        }
        bf16x8 pf0 = *(const bf16x8*)(pw + lrow * PAD + lq * 8);
        bf16x8 pf1 = *(const bf16x8*)(pw + lrow * PAD + 32 + lq * 8);
        #pragma unroll
        for (int dt = 0; dt < 4; dt++) {
            const unsigned short* vp = lds_v + (dt * 16 + lrow) * PAD + lq * 8;
            o_acc[dt] = mfma16(pf0, *(const bf16x8*)vp, o_acc[dt]);
            o_acc[dt] = mfma16(pf1, *(const bf16x8*)(vp + 32), o_acc[dt]);
        }
    }
    // one cross-lane reduction of l at the end (lanes sharing lq hold the row's 16 col-partials)
    #pragma unroll
    for (int r = 0; r < 4; r++) {
        float s = l_run[r];
        s += __shfl_xor(s, 1);
        s += __shfl_xor(s, 2);
        s += __shfl_xor(s, 4);
        s += __shfl_xor(s, 8);
        l_run[r] = 1.0f / s;
    }
    int h = bh & 15, b = bh >> 4;
    #pragma unroll
    for (int dt = 0; dt < 4; dt++)
        #pragma unroll
        for (int r = 0; r < 4; r++) {
            int i = i0 + w * 16 + lq * 4 + r;
            int d = dt * 16 + lrow;
            float v = o_acc[dt][r] * l_run[r];
            att[((long)(b * T_SEQ + i)) * D_MODEL + h * 64 + d] = f32_bf16(v);
        }
}

// ---------------- LayerNorm in-place on d_out ----------------
__global__ __launch_bounds__(256) void k_ln(float* __restrict__ io,
                                            const float* __restrict__ gamma,
                                            const float* __restrict__ beta) {
    int row = blockIdx.x, t = threadIdx.x;
    float* p = io + (long)row * D_MODEL + t * 4;
    float4 v = *(float4*)p;
    float s = v.x + v.y + v.z + v.w;
    float ss = v.x * v.x + v.y * v.y + v.z * v.z + v.w * v.w;
    #pragma unroll
    for (int m = 1; m < 64; m <<= 1) {
        s += __shfl_xor(s, m);
        ss += __shfl_xor(ss, m);
    }
    __shared__ float red[8];
    if ((t & 63) == 0) { red[t >> 6] = s; red[4 + (t >> 6)] = ss; }
    __syncthreads();
    s = red[0] + red[1] + red[2] + red[3];
    ss = red[4] + red[5] + red[6] + red[7];
    float mu = s * (1.0f / 1024.0f);
    float var = ss * (1.0f / 1024.0f) - mu * mu;
    float rstd = rsqrtf(var + 1e-5f);
    float4 g = *(const float4*)(gamma + t * 4);
    float4 be = *(const float4*)(beta + t * 4);
    float4 o;
    o.x = (v.x - mu) * rstd * g.x + be.x;
    o.y = (v.y - mu) * rstd * g.y + be.y;
    o.z = (v.z - mu) * rstd * g.z + be.z;
    o.w = (v.w - mu) * rstd * g.w + be.w;
    *(float4*)p = o;
}

extern "C" void kernel_launch(void* const* d_in, const int* in_sizes, int n_in,
                              void* d_out, int out_size, void* d_ws, size_t ws_size,
                              hipStream_t stream) {
    const float* x = (const float*)d_in[0];
    const float* Wq = (const float*)d_in[1];
    const float* bq = (const float*)d_in[2];
    const float* Wk = (const float*)d_in[3];
    const float* bk = (const float*)d_in[4];
    const float* Wv = (const float*)d_in[5];
    const float* bv = (const float*)d_in[6];
    const float* Wo = (const float*)d_in[7];
    const float* bo = (const float*)d_in[8];
    const float* gamma = (const float*)d_in[9];
    const float* beta = (const float*)d_in[10];
    float* out = (float*)d_out;

    char* ws = (char*)d_ws;
    unsigned short* x_bf = (unsigned short*)(ws);                       // 8 MB (reused as att)
    unsigned short* wqkv_bf = (unsigned short*)(ws + ((size_t)8 << 20));// 6 MB (Wq|Wk|Wv stacked)
    unsigned short* wo_bf = (unsigned short*)(ws + ((size_t)14 << 20)); // 2 MB
    unsigned short* qkv_ws = (unsigned short*)(ws + ((size_t)16 << 20));// 24 MB (q|k|v)
    unsigned short* vt_ws = (unsigned short*)(ws + ((size_t)40 << 20)); // 8 MB
    unsigned short* att = x_bf;  // alias: x_bf dead after QKV GEMM

    unsigned short* q_ws = qkv_ws;
    unsigned short* k_ws = qkv_ws + (size_t)32 * T_SEQ * DH;
    unsigned short* v_ws = qkv_ws + (size_t)64 * T_SEQ * DH;

    k_conv_x<<<NROWS * D_MODEL / 1024, 256, 0, stream>>>(x, x_bf);
    k_conv_wperm_row<<<1024, 256, 0, stream>>>(Wq, wqkv_bf);
    k_conv_wperm_row<<<1024, 256, 0, stream>>>(Wk, wqkv_bf + (size_t)1024 * D_MODEL);
    k_conv_wperm_row<<<1024, 256, 0, stream>>>(Wv, wqkv_bf + (size_t)2048 * D_MODEL);
    k_conv_wo<<<1024, 256, 0, stream>>>(Wo, wo_bf);

    // fused QKV GEMM: N = 3072
    k_gemm<128, 0><<<dim3(NROWS / 128, 24), 256, 0, stream>>>(
        x_bf, wqkv_bf, bq, bk, bv, nullptr, qkv_ws, nullptr);

    k_vtrans<<<dim3(T_SEQ / 64, 32), 256, 0, stream>>>(v_ws, vt_ws);
    k_attn<<<dim3(T_SEQ / 64, 32), 256, 0, stream>>>(q_ws, k_ws, vt_ws, att);

    // O-projection + bias + residual
    k_gemm<64, 1><<<dim3(NROWS / 128, D_MODEL / 64), 256, 0, stream>>>(
        att, wo_bf, bo, nullptr, nullptr, x, nullptr, out);

    k_ln<<<NROWS, 256, 0, stream>>>(out, gamma, beta);
}

// Round 4
// 234.727 us; speedup vs baseline: 1.5851x; 1.1232x over previous
//
#include <hip/hip_runtime.h>
#include <stdint.h>

#define T_SEQ 2048
#define D_MODEL 1024
#define NH 16
#define DH 64
#define NROWS 4096  // B*T

typedef __bf16 bf16x8 __attribute__((ext_vector_type(8)));
typedef float floatx4 __attribute__((ext_vector_type(4)));
typedef short short4v __attribute__((ext_vector_type(4)));
typedef short short8v __attribute__((ext_vector_type(8)));

#define AS1 __attribute__((address_space(1)))
#define AS3 __attribute__((address_space(3)))

static __device__ __forceinline__ void gl2lds16(const unsigned short* g, unsigned short* s) {
    __builtin_amdgcn_global_load_lds((const AS1 unsigned int*)g, (AS3 unsigned int*)s, 16, 0, 0);
}

static __device__ __forceinline__ unsigned short f32_bf16(float f) {
    union { float f; unsigned int u; } c; c.f = f;
    unsigned int u = c.u;
    u = u + 0x7FFFu + ((u >> 16) & 1u);   // RNE
    return (unsigned short)(u >> 16);
}

static __device__ __forceinline__ unsigned int pack2_bf16(float a, float b) {
    return (unsigned int)f32_bf16(a) | ((unsigned int)f32_bf16(b) << 16);
}

static __device__ __forceinline__ floatx4 mfma16(bf16x8 a, bf16x8 b, floatx4 c) {
    return __builtin_amdgcn_mfma_f32_16x16x32_bf16(a, b, c, 0, 0, 0);
}

static __device__ __forceinline__ floatx4 mfma16k16(short4v a, short4v b, floatx4 c) {
#if defined(__HIP_DEVICE_COMPILE__)
    return __builtin_amdgcn_mfma_f32_16x16x16bf16_1k(a, b, c, 0, 0, 0);
#else
    (void)a; (void)b;
    return c;  // host stub — never executed
#endif
}

#define QSCALE 0.1803368801111204f   // (1/8) * log2(e); softmax in exp2 domain
#define EXP2_SHIFT 10.0f

// ---------------- conversion kernels ----------------

__global__ __launch_bounds__(256) void k_conv_x(const float* __restrict__ src,
                                                unsigned short* __restrict__ dst) {
    int i = (blockIdx.x * 256 + threadIdx.x) * 4;
    float4 v = *(const float4*)(src + i);
    uint2 o;
    o.x = pack2_bf16(v.x, v.y);
    o.y = pack2_bf16(v.z, v.w);
    *(uint2*)(dst + i) = o;
}

// W row-permuted (Q,K,V fused): dst row n' = h*64+d  <=  src row f = (n'&63)*16 + (n'>>6)
__global__ __launch_bounds__(256) void k_conv_wperm_row(const float* __restrict__ s0,
                                                        const float* __restrict__ s1,
                                                        const float* __restrict__ s2,
                                                        unsigned short* __restrict__ dst) {
    int tensor = blockIdx.y;
    const float* src = tensor == 0 ? s0 : tensor == 1 ? s1 : s2;
    int np = blockIdx.x;
    int f = (np & 63) * 16 + (np >> 6);
    int c = threadIdx.x * 4;
    float4 v = *(const float4*)(src + (long)f * D_MODEL + c);
    uint2 o;
    o.x = pack2_bf16(v.x, v.y);
    o.y = pack2_bf16(v.z, v.w);
    *(uint2*)(dst + ((long)tensor * D_MODEL + np) * D_MODEL + c) = o;
}

// Wo column-permuted: dst[n][f'] = src[n][(f'&63)*16 + (f'>>6)]
__global__ __launch_bounds__(256) void k_conv_wo(const float* __restrict__ src,
                                                 unsigned short* __restrict__ dst) {
    int n = blockIdx.x;
    int fp = threadIdx.x * 4;
    const float* row = src + (long)n * D_MODEL;
    unsigned short o[4];
    #pragma unroll
    for (int k = 0; k < 4; k++) {
        int f = fp + k;
        o[k] = f32_bf16(row[(f & 63) * 16 + (f >> 6)]);
    }
    *(uint2*)(dst + (long)n * D_MODEL + fp) = *(const uint2*)o;
}

// ---------------- GEMM: C = A(bf16) @ W(bf16)^T, K = 1024, m97-style ----------------
// BM=128, BK=64, 256 threads = 4 waves in 2x2; wave tile 64 x (BN/2).
// MODE 0: fused QKV (W stacked 3072x1024). Q/K -> [bh][i][d] bf16 (Q scaled);
//         V -> vtg[bh][d][blk][j'] pre-permuted for 16x16x16 A-frags.
// MODE 1: O-projection; out = acc + bo[n] + resid -> fp32 [row][n]
template <int BN, int MODE>
__global__ __launch_bounds__(256) void k_gemm(const unsigned short* __restrict__ A,
                                              const unsigned short* __restrict__ W,
                                              const float* __restrict__ b0,
                                              const float* __restrict__ b1,
                                              const float* __restrict__ b2,
                                              const float* __restrict__ resid,
                                              unsigned short* __restrict__ out_bf,
                                              unsigned short* __restrict__ vtg,
                                              float* __restrict__ out_f32) {
    constexpr int NT = BN / 32;
    constexpr int NCB = BN / 32;
    __shared__ unsigned short lds_a[128 * 64];
    __shared__ unsigned short lds_b[BN * 64];
    const int tid = threadIdx.x;
    const int w = tid >> 6, l = tid & 63;
    const int lrow = l & 15, lq = l >> 4;
    const int wm = (w >> 1) * 64, wn = (w & 1) * (BN / 2);
    const long am0 = (long)blockIdx.x * 128;
    const long wn0 = (long)blockIdx.y * BN;

    floatx4 acc[4][NT] = {};
    const int grow = l >> 3, gcol = (l & 7) * 8;

    for (int k0 = 0; k0 < D_MODEL; k0 += 64) {
        #pragma unroll
        for (int c = 0; c < 4; c++) {
            int chunk = w * 4 + c;
            gl2lds16(A + (am0 + chunk * 8 + grow) * D_MODEL + k0 + gcol,
                     lds_a + chunk * 512);
        }
        #pragma unroll
        for (int c = 0; c < NCB; c++) {
            int chunk = w * NCB + c;
            gl2lds16(W + (wn0 + chunk * 8 + grow) * D_MODEL + k0 + gcol,
                     lds_b + chunk * 512);
        }
        __syncthreads();

        bf16x8 af[4][2], bf[NT][2];
        #pragma unroll
        for (int mt = 0; mt < 4; mt++)
            #pragma unroll
            for (int ks = 0; ks < 2; ks++)
                af[mt][ks] = *(const bf16x8*)(lds_a + (wm + mt * 16 + lrow) * 64 + ks * 32 + lq * 8);
        #pragma unroll
        for (int nt = 0; nt < NT; nt++)
            #pragma unroll
            for (int ks = 0; ks < 2; ks++)
                bf[nt][ks] = *(const bf16x8*)(lds_b + (wn + nt * 16 + lrow) * 64 + ks * 32 + lq * 8);
        #pragma unroll
        for (int mt = 0; mt < 4; mt++)
            #pragma unroll
            for (int nt = 0; nt < NT; nt++)
                #pragma unroll
                for (int ks = 0; ks < 2; ks++)
                    acc[mt][nt] = mfma16(af[mt][ks], bf[nt][ks], acc[mt][nt]);
        __syncthreads();
    }

    if (MODE == 0) {
        int tensor = blockIdx.y >> 3;                    // 0=Q 1=K 2=V
        int nbase = (blockIdx.y & 7) * 128;
        const float* bias = tensor == 0 ? b0 : tensor == 1 ? b1 : b2;
        float scale = tensor == 0 ? QSCALE : 1.0f;
        if (tensor < 2) {
            unsigned short* outt = out_bf + (size_t)tensor * (32u * T_SEQ * DH);
            #pragma unroll
            for (int mt = 0; mt < 4; mt++) {
                #pragma unroll
                for (int nt = 0; nt < NT; nt++) {
                    int n = nbase + wn + nt * 16 + lrow;     // n' = h*64+d
                    int h = n >> 6, d = n & 63;
                    float bb = bias[d * 16 + h];
                    #pragma unroll
                    for (int r = 0; r < 4; r++) {
                        int row = (int)am0 + wm + mt * 16 + lq * 4 + r;
                        float v = (acc[mt][nt][r] + bb) * scale;
                        int b = row >> 11, i = row & 2047;
                        long idx = ((long)(b * 16 + h) * T_SEQ + i) * DH + d;
                        outt[idx] = f32_bf16(v);
                    }
                }
            }
        } else {
            // V -> vtg[((bh*64+d)*32 + blk)*64 + j'], j' = lq*16 + mt*4 + r
            int row0 = (int)am0 + wm;                    // multiple of 64
            int b = row0 >> 11;
            int blk = (row0 & 2047) >> 6;
            #pragma unroll
            for (int nt = 0; nt < NT; nt++) {
                int n = nbase + wn + nt * 16 + lrow;
                int h = n >> 6, d = n & 63;
                float bb = bias[d * 16 + h];
                long base = (((long)(b * 16 + h) * 64 + d) * 32 + blk) * 64;
                #pragma unroll
                for (int mt = 0; mt < 4; mt++) {
                    uint2 o;
                    o.x = pack2_bf16(acc[mt][nt][0] + bb, acc[mt][nt][1] + bb);
                    o.y = pack2_bf16(acc[mt][nt][2] + bb, acc[mt][nt][3] + bb);
                    *(uint2*)(vtg + base + lq * 16 + mt * 4) = o;
                }
            }
        }
    } else {
        #pragma unroll
        for (int mt = 0; mt < 4; mt++) {
            #pragma unroll
            for (int nt = 0; nt < NT; nt++) {
                int n = (int)wn0 + wn + nt * 16 + lrow;
                float bb = b0[n];
                #pragma unroll
                for (int r = 0; r < 4; r++) {
                    int row = (int)am0 + wm + mt * 16 + lq * 4 + r;
                    long idx = (long)row * D_MODEL + n;
                    out_f32[idx] = acc[mt][nt][r] + bb + resid[idx];
                }
            }
        }
    }
}

// ---------------- attention: S^T trick, P stays in registers ----------------
// S^T = mfma(A=K, B=Q) -> lane holds P[i=lrow][j=lq*4+r]  == B-frag of 16x16x16.
// O^T = mfma16x16(A=V^T-frag, B=P-frag); l via A=ones MFMA (complete per-lane).
#define PAD 72
__global__ __launch_bounds__(256) void k_attn(const unsigned short* __restrict__ q_ws,
                                              const unsigned short* __restrict__ k_ws,
                                              const unsigned short* __restrict__ vtg,
                                              unsigned short* __restrict__ att) {
    __shared__ unsigned short lds_k[64 * PAD];
    __shared__ unsigned short lds_v[64 * PAD];
    const int tid = threadIdx.x;
    const int w = tid >> 6, l = tid & 63;
    const int lrow = l & 15, lq = l >> 4;
    const int bh = blockIdx.y;
    const int i0 = blockIdx.x * 64;
    const unsigned short* kh = k_ws + (long)bh * T_SEQ * DH;
    const unsigned short* vh = vtg + (long)bh * 64 * T_SEQ;  // [d][blk][j']

    bf16x8 qf[2];
    {
        const unsigned short* qp = q_ws + ((long)bh * T_SEQ + i0 + w * 16 + lrow) * DH + lq * 8;
        qf[0] = *(const bf16x8*)qp;
        qf[1] = *(const bf16x8*)(qp + 32);
    }
    floatx4 o_acc[4] = {};
    floatx4 l_acc = {};
    const short4v ones = {0x3F80, 0x3F80, 0x3F80, 0x3F80};

    const int srow = tid >> 3, scol = (tid & 7) * 8;
    for (int jt = 0; jt < T_SEQ / 64; jt++) {
        int j0 = jt * 64;
        __syncthreads();
        *(uint4*)(lds_k + srow * PAD + scol) = *(const uint4*)(kh + (long)(j0 + srow) * DH + scol);
        *(uint4*)(lds_k + (srow + 32) * PAD + scol) = *(const uint4*)(kh + (long)(j0 + srow + 32) * DH + scol);
        *(uint4*)(lds_v + srow * PAD + scol) = *(const uint4*)(vh + ((long)srow * 32 + jt) * 64 + scol);
        *(uint4*)(lds_v + (srow + 32) * PAD + scol) = *(const uint4*)(vh + ((long)(srow + 32) * 32 + jt) * 64 + scol);
        __syncthreads();

        // S^T - 10 (shift folded into acc init)
        floatx4 s[4];
        #pragma unroll
        for (int nt = 0; nt < 4; nt++) {
            floatx4 c = {-EXP2_SHIFT, -EXP2_SHIFT, -EXP2_SHIFT, -EXP2_SHIFT};
            const unsigned short* kp = lds_k + (nt * 16 + lrow) * PAD + lq * 8;
            c = mfma16(*(const bf16x8*)kp, qf[0], c);
            c = mfma16(*(const bf16x8*)(kp + 32), qf[1], c);
            s[nt] = c;
        }
        // p = exp2(s); pack to bf16 B-frags; l via ones-MFMA
        short4v pf[4];
        #pragma unroll
        for (int nt = 0; nt < 4; nt++) {
            float p0 = __builtin_amdgcn_exp2f(s[nt][0]);
            float p1 = __builtin_amdgcn_exp2f(s[nt][1]);
            float p2 = __builtin_amdgcn_exp2f(s[nt][2]);
            float p3 = __builtin_amdgcn_exp2f(s[nt][3]);
            uint2 pk;
            pk.x = __builtin_amdgcn_perm(__float_as_uint(p1), __float_as_uint(p0), 0x07060302);
            pk.y = __builtin_amdgcn_perm(__float_as_uint(p3), __float_as_uint(p2), 0x07060302);
            union { uint2 u; short4v s4; } cv; cv.u = pk;
            pf[nt] = cv.s4;
            l_acc = mfma16k16(ones, pf[nt], l_acc);
        }
        // O^T += V^T * P
        #pragma unroll
        for (int dt = 0; dt < 4; dt++) {
            const unsigned short* vp = lds_v + (dt * 16 + lrow) * PAD + lq * 16;
            short8v v01 = *(const short8v*)vp;
            short8v v23 = *(const short8v*)(vp + 8);
            o_acc[dt] = mfma16k16(__builtin_shufflevector(v01, v01, 0, 1, 2, 3), pf[0], o_acc[dt]);
            o_acc[dt] = mfma16k16(__builtin_shufflevector(v01, v01, 4, 5, 6, 7), pf[1], o_acc[dt]);
            o_acc[dt] = mfma16k16(__builtin_shufflevector(v23, v23, 0, 1, 2, 3), pf[2], o_acc[dt]);
            o_acc[dt] = mfma16k16(__builtin_shufflevector(v23, v23, 4, 5, 6, 7), pf[3], o_acc[dt]);
        }
    }
    // l_acc[any r] = full softmax denom for row i = lrow
    float rl = 1.0f / l_acc[0];
    int h = bh & 15, b = bh >> 4;
    int i = i0 + w * 16 + lrow;
    unsigned short* orow = att + ((long)(b * T_SEQ + i)) * D_MODEL + h * 64;
    #pragma unroll
    for (int dt = 0; dt < 4; dt++) {
        uint2 o;
        o.x = pack2_bf16(o_acc[dt][0] * rl, o_acc[dt][1] * rl);
        o.y = pack2_bf16(o_acc[dt][2] * rl, o_acc[dt][3] * rl);
        *(uint2*)(orow + dt * 16 + lq * 4) = o;
    }
}

// ---------------- LayerNorm in-place on d_out ----------------
__global__ __launch_bounds__(256) void k_ln(float* __restrict__ io,
                                            const float* __restrict__ gamma,
                                            const float* __restrict__ beta) {
    int row = blockIdx.x, t = threadIdx.x;
    float* p = io + (long)row * D_MODEL + t * 4;
    float4 v = *(float4*)p;
    float s = v.x + v.y + v.z + v.w;
    float ss = v.x * v.x + v.y * v.y + v.z * v.z + v.w * v.w;
    #pragma unroll
    for (int m = 1; m < 64; m <<= 1) {
        s += __shfl_xor(s, m);
        ss += __shfl_xor(ss, m);
    }
    __shared__ float red[8];
    if ((t & 63) == 0) { red[t >> 6] = s; red[4 + (t >> 6)] = ss; }
    __syncthreads();
    s = red[0] + red[1] + red[2] + red[3];
    ss = red[4] + red[5] + red[6] + red[7];
    float mu = s * (1.0f / 1024.0f);
    float var = ss * (1.0f / 1024.0f) - mu * mu;
    float rstd = rsqrtf(var + 1e-5f);
    float4 g = *(const float4*)(gamma + t * 4);
    float4 be = *(const float4*)(beta + t * 4);
    float4 o;
    o.x = (v.x - mu) * rstd * g.x + be.x;
    o.y = (v.y - mu) * rstd * g.y + be.y;
    o.z = (v.z - mu) * rstd * g.z + be.z;
    o.w = (v.w - mu) * rstd * g.w + be.w;
    *(float4*)p = o;
}

extern "C" void kernel_launch(void* const* d_in, const int* in_sizes, int n_in,
                              void* d_out, int out_size, void* d_ws, size_t ws_size,
                              hipStream_t stream) {
    const float* x = (const float*)d_in[0];
    const float* Wq = (const float*)d_in[1];
    const float* bq = (const float*)d_in[2];
    const float* Wk = (const float*)d_in[3];
    const float* bk = (const float*)d_in[4];
    const float* Wv = (const float*)d_in[5];
    const float* bv = (const float*)d_in[6];
    const float* Wo = (const float*)d_in[7];
    const float* bo = (const float*)d_in[8];
    const float* gamma = (const float*)d_in[9];
    const float* beta = (const float*)d_in[10];
    float* out = (float*)d_out;

    char* ws = (char*)d_ws;
    unsigned short* x_bf = (unsigned short*)(ws);                       // 8 MB (reused as att)
    unsigned short* wqkv_bf = (unsigned short*)(ws + ((size_t)8 << 20));// 6 MB
    unsigned short* wo_bf = (unsigned short*)(ws + ((size_t)14 << 20)); // 2 MB
    unsigned short* qkv_ws = (unsigned short*)(ws + ((size_t)16 << 20));// 24 MB (q|k|vt)
    unsigned short* att = x_bf;  // alias: x_bf dead after QKV GEMM

    unsigned short* q_ws = qkv_ws;
    unsigned short* k_ws = qkv_ws + (size_t)32 * T_SEQ * DH;
    unsigned short* vtg = qkv_ws + (size_t)64 * T_SEQ * DH;

    k_conv_x<<<NROWS * D_MODEL / 1024, 256, 0, stream>>>(x, x_bf);
    k_conv_wperm_row<<<dim3(1024, 3), 256, 0, stream>>>(Wq, Wk, Wv, wqkv_bf);
    k_conv_wo<<<1024, 256, 0, stream>>>(Wo, wo_bf);

    // fused QKV GEMM: N = 3072
    k_gemm<128, 0><<<dim3(NROWS / 128, 24), 256, 0, stream>>>(
        x_bf, wqkv_bf, bq, bk, bv, nullptr, qkv_ws, vtg, nullptr);

    k_attn<<<dim3(T_SEQ / 64, 32), 256, 0, stream>>>(q_ws, k_ws, vtg, att);

    // O-projection + bias + residual
    k_gemm<64, 1><<<dim3(NROWS / 128, D_MODEL / 64), 256, 0, stream>>>(
        att, wo_bf, bo, nullptr, nullptr, x, nullptr, nullptr, out);

    k_ln<<<NROWS, 256, 0, stream>>>(out, gamma, beta);
}

// Round 5
// 218.795 us; speedup vs baseline: 1.7005x; 1.0728x over previous
//
#include <hip/hip_runtime.h>
#include <stdint.h>

#define T_SEQ 2048
#define D_MODEL 1024
#define NH 16
#define DH 64
#define NROWS 4096  // B*T

typedef __bf16 bf16x8 __attribute__((ext_vector_type(8)));
typedef float floatx4 __attribute__((ext_vector_type(4)));
typedef short short4v __attribute__((ext_vector_type(4)));
typedef short short8v __attribute__((ext_vector_type(8)));

#define AS1 __attribute__((address_space(1)))
#define AS3 __attribute__((address_space(3)))

static __device__ __forceinline__ void gl2lds16(const unsigned short* g, unsigned short* s) {
    __builtin_amdgcn_global_load_lds((const AS1 unsigned int*)g, (AS3 unsigned int*)s, 16, 0, 0);
}

static __device__ __forceinline__ unsigned short f32_bf16(float f) {
    union { float f; unsigned int u; } c; c.f = f;
    unsigned int u = c.u;
    u = u + 0x7FFFu + ((u >> 16) & 1u);   // RNE
    return (unsigned short)(u >> 16);
}

static __device__ __forceinline__ unsigned int pack2_bf16(float a, float b) {
    return (unsigned int)f32_bf16(a) | ((unsigned int)f32_bf16(b) << 16);
}

static __device__ __forceinline__ floatx4 mfma16(bf16x8 a, bf16x8 b, floatx4 c) {
    return __builtin_amdgcn_mfma_f32_16x16x32_bf16(a, b, c, 0, 0, 0);
}

static __device__ __forceinline__ floatx4 mfma16k16(short4v a, short4v b, floatx4 c) {
#if defined(__HIP_DEVICE_COMPILE__)
    return __builtin_amdgcn_mfma_f32_16x16x16bf16_1k(a, b, c, 0, 0, 0);
#else
    (void)a; (void)b;
    return c;  // host stub — never executed
#endif
}

#define QSCALE 0.1803368801111204f   // (1/8) * log2(e); softmax in exp2 domain
#define EXP2_SHIFT 10.0f

// ---------------- fused conversion kernel ----------------
// blocks 0..4095: x fp32->bf16; 4096..7167: Wq/Wk/Wv row-permute; 7168..8191: Wo col-permute
__global__ __launch_bounds__(256) void k_conv_all(const float* __restrict__ x,
                                                  const float* __restrict__ Wq,
                                                  const float* __restrict__ Wk,
                                                  const float* __restrict__ Wv,
                                                  const float* __restrict__ Wo,
                                                  unsigned short* __restrict__ x_bf,
                                                  unsigned short* __restrict__ wqkv_bf,
                                                  unsigned short* __restrict__ wo_bf) {
    int b = blockIdx.x, t = threadIdx.x;
    if (b < 4096) {
        int i = b * 1024 + t * 4;
        float4 v = *(const float4*)(x + i);
        uint2 o;
        o.x = pack2_bf16(v.x, v.y);
        o.y = pack2_bf16(v.z, v.w);
        *(uint2*)(x_bf + i) = o;
    } else if (b < 7168) {
        int idx = b - 4096;
        int tensor = idx >> 10, np = idx & 1023;
        const float* src = tensor == 0 ? Wq : tensor == 1 ? Wk : Wv;
        int f = (np & 63) * 16 + (np >> 6);
        int c = t * 4;
        float4 v = *(const float4*)(src + (long)f * D_MODEL + c);
        uint2 o;
        o.x = pack2_bf16(v.x, v.y);
        o.y = pack2_bf16(v.z, v.w);
        *(uint2*)(wqkv_bf + ((long)tensor * D_MODEL + np) * D_MODEL + c) = o;
    } else {
        int n = b - 7168;
        int fp = t * 4;
        const float* row = Wo + (long)n * D_MODEL;
        unsigned short o[4];
        #pragma unroll
        for (int k = 0; k < 4; k++) {
            int f = fp + k;
            o[k] = f32_bf16(row[(f & 63) * 16 + (f >> 6)]);
        }
        *(uint2*)(wo_bf + (long)n * D_MODEL + fp) = *(const uint2*)o;
    }
}

// ---------------- GEMM: C = A(bf16) @ W(bf16)^T, K = 1024 ----------------
// BM=128, BK=64, 256 threads = 4 waves 2x2; XOR-swizzled LDS (conflict-free frag reads
// while keeping global_load_lds lane-order); XCD-aware 1D block swizzle.
// LDS layout: element (row r, colgroup cg of 8) lives at r*64 + ((cg ^ (r&7))*8).
// MODE 0: fused QKV (W stacked 3072x1024); grid 768. MODE 1: O-proj; grid 512.
template <int BN, int MODE>
__global__ __launch_bounds__(256) void k_gemm(const unsigned short* __restrict__ A,
                                              const unsigned short* __restrict__ W,
                                              const float* __restrict__ b0,
                                              const float* __restrict__ b1,
                                              const float* __restrict__ b2,
                                              const float* __restrict__ resid,
                                              unsigned short* __restrict__ out_bf,
                                              unsigned short* __restrict__ vtg,
                                              float* __restrict__ out_f32) {
    constexpr int NT = BN / 32;
    constexpr int NCB = BN / 32;
    __shared__ unsigned short lds_a[128 * 64];
    __shared__ unsigned short lds_b[BN * 64];
    const int tid = threadIdx.x;
    const int w = tid >> 6, l = tid & 63;
    const int lrow = l & 15, lq = l >> 4;
    const int wm = (w >> 1) * 64, wn = (w & 1) * (BN / 2);
    // XCD swizzle: same x-tile stays on one XCD (assumes xcd = linearID % 8)
    const int L = blockIdx.x;
    const int bx = (L & 7) * 4 + ((L >> 3) & 3);
    const int by = L >> 5;
    const long am0 = (long)bx * 128;
    const long wn0 = (long)by * BN;

    floatx4 acc[4][NT] = {};
    const int grow = l >> 3;
    const int gcol = ((l & 7) ^ grow) * 8;    // column-group XOR swizzle on the global side
    const int sw8 = (lrow & 7);

    for (int k0 = 0; k0 < D_MODEL; k0 += 64) {
        #pragma unroll
        for (int c = 0; c < 4; c++) {
            int chunk = w * 4 + c;
            gl2lds16(A + (am0 + chunk * 8 + grow) * D_MODEL + k0 + gcol,
                     lds_a + chunk * 512);
        }
        #pragma unroll
        for (int c = 0; c < NCB; c++) {
            int chunk = w * NCB + c;
            gl2lds16(W + (wn0 + chunk * 8 + grow) * D_MODEL + k0 + gcol,
                     lds_b + chunk * 512);
        }
        __syncthreads();

        bf16x8 af[4][2], bf[NT][2];
        #pragma unroll
        for (int mt = 0; mt < 4; mt++)
            #pragma unroll
            for (int ks = 0; ks < 2; ks++)
                af[mt][ks] = *(const bf16x8*)(lds_a + (wm + mt * 16 + lrow) * 64 +
                                              (((ks * 4 + lq) ^ sw8) * 8));
        #pragma unroll
        for (int nt = 0; nt < NT; nt++)
            #pragma unroll
            for (int ks = 0; ks < 2; ks++)
                bf[nt][ks] = *(const bf16x8*)(lds_b + (wn + nt * 16 + lrow) * 64 +
                                              (((ks * 4 + lq) ^ sw8) * 8));
        #pragma unroll
        for (int mt = 0; mt < 4; mt++)
            #pragma unroll
            for (int nt = 0; nt < NT; nt++)
                #pragma unroll
                for (int ks = 0; ks < 2; ks++)
                    acc[mt][nt] = mfma16(af[mt][ks], bf[nt][ks], acc[mt][nt]);
        __syncthreads();
    }

    if (MODE == 0) {
        int tensor = by >> 3;                    // 0=Q 1=K 2=V
        int nbase = (by & 7) * 128;
        const float* bias = tensor == 0 ? b0 : tensor == 1 ? b1 : b2;
        float scale = tensor == 0 ? QSCALE : 1.0f;
        if (tensor < 2) {
            unsigned short* outt = out_bf + (size_t)tensor * (32u * T_SEQ * DH);
            #pragma unroll
            for (int mt = 0; mt < 4; mt++) {
                #pragma unroll
                for (int nt = 0; nt < NT; nt++) {
                    int n = nbase + wn + nt * 16 + lrow;     // n' = h*64+d
                    int h = n >> 6, d = n & 63;
                    float bb = bias[d * 16 + h];
                    #pragma unroll
                    for (int r = 0; r < 4; r++) {
                        int row = (int)am0 + wm + mt * 16 + lq * 4 + r;
                        float v = (acc[mt][nt][r] + bb) * scale;
                        int b = row >> 11, i = row & 2047;
                        long idx = ((long)(b * 16 + h) * T_SEQ + i) * DH + d;
                        outt[idx] = f32_bf16(v);
                    }
                }
            }
        } else {
            // V -> vtg[((bh*64+d)*32 + blk)*64 + j'], j' = lq*16 + mt*4 + r
            int row0 = (int)am0 + wm;                    // multiple of 64
            int b = row0 >> 11;
            int blk = (row0 & 2047) >> 6;
            #pragma unroll
            for (int nt = 0; nt < NT; nt++) {
                int n = nbase + wn + nt * 16 + lrow;
                int h = n >> 6, d = n & 63;
                float bb = bias[d * 16 + h];
                long base = (((long)(b * 16 + h) * 64 + d) * 32 + blk) * 64;
                #pragma unroll
                for (int mt = 0; mt < 4; mt++) {
                    uint2 o;
                    o.x = pack2_bf16(acc[mt][nt][0] + bb, acc[mt][nt][1] + bb);
                    o.y = pack2_bf16(acc[mt][nt][2] + bb, acc[mt][nt][3] + bb);
                    *(uint2*)(vtg + base + lq * 16 + mt * 4) = o;
                }
            }
        }
    } else {
        #pragma unroll
        for (int mt = 0; mt < 4; mt++) {
            #pragma unroll
            for (int nt = 0; nt < NT; nt++) {
                int n = (int)wn0 + wn + nt * 16 + lrow;
                float bb = b0[n];
                #pragma unroll
                for (int r = 0; r < 4; r++) {
                    int row = (int)am0 + wm + mt * 16 + lq * 4 + r;
                    long idx = (long)row * D_MODEL + n;
                    out_f32[idx] = acc[mt][nt][r] + bb + resid[idx];
                }
            }
        }
    }
}

// ---------------- attention: S^T trick, 2 Q-tiles per wave ----------------
// Block covers 128 q-rows; wave w owns rows i0+w*32+{0..31} (2 tiles of 16).
// K/V frag reads shared across both Q-tiles. Grid 512, XCD-swizzled by bh.
#define PAD 72
__global__ __launch_bounds__(256) void k_attn(const unsigned short* __restrict__ q_ws,
                                              const unsigned short* __restrict__ k_ws,
                                              const unsigned short* __restrict__ vtg,
                                              unsigned short* __restrict__ att) {
    __shared__ unsigned short lds_k[64 * PAD];
    __shared__ unsigned short lds_v[64 * PAD];
    const int tid = threadIdx.x;
    const int w = tid >> 6, l = tid & 63;
    const int lrow = l & 15, lq = l >> 4;
    const int L = blockIdx.x;
    const int bh = (L & 7) * 4 + ((L >> 3) & 3);   // 4 bh per XCD -> K/V L2-resident
    const int i0 = (L >> 5) * 128;
    const unsigned short* kh = k_ws + (long)bh * T_SEQ * DH;
    const unsigned short* vh = vtg + (long)bh * 64 * T_SEQ;  // [d][blk][j']

    bf16x8 qf[2][2];
    #pragma unroll
    for (int qt = 0; qt < 2; qt++) {
        const unsigned short* qp =
            q_ws + ((long)bh * T_SEQ + i0 + w * 32 + qt * 16 + lrow) * DH + lq * 8;
        qf[qt][0] = *(const bf16x8*)qp;
        qf[qt][1] = *(const bf16x8*)(qp + 32);
    }
    floatx4 o_acc[2][4] = {};
    floatx4 l_acc[2] = {};
    const short4v ones = {0x3F80, 0x3F80, 0x3F80, 0x3F80};

    const int srow = tid >> 3, scol = (tid & 7) * 8;
    for (int jt = 0; jt < T_SEQ / 64; jt++) {
        int j0 = jt * 64;
        __syncthreads();
        *(uint4*)(lds_k + srow * PAD + scol) = *(const uint4*)(kh + (long)(j0 + srow) * DH + scol);
        *(uint4*)(lds_k + (srow + 32) * PAD + scol) = *(const uint4*)(kh + (long)(j0 + srow + 32) * DH + scol);
        *(uint4*)(lds_v + srow * PAD + scol) = *(const uint4*)(vh + ((long)srow * 32 + jt) * 64 + scol);
        *(uint4*)(lds_v + (srow + 32) * PAD + scol) = *(const uint4*)(vh + ((long)(srow + 32) * 32 + jt) * 64 + scol);
        __syncthreads();

        // S^T - 10 for both q-tiles; K-frags read once
        floatx4 s0[4], s1[4];
        #pragma unroll
        for (int nt = 0; nt < 4; nt++) {
            const unsigned short* kp = lds_k + (nt * 16 + lrow) * PAD + lq * 8;
            bf16x8 ka = *(const bf16x8*)kp;
            bf16x8 kb = *(const bf16x8*)(kp + 32);
            floatx4 c0 = {-EXP2_SHIFT, -EXP2_SHIFT, -EXP2_SHIFT, -EXP2_SHIFT};
            floatx4 c1 = c0;
            c0 = mfma16(ka, qf[0][0], c0);
            c0 = mfma16(kb, qf[0][1], c0);
            c1 = mfma16(ka, qf[1][0], c1);
            c1 = mfma16(kb, qf[1][1], c1);
            s0[nt] = c0;
            s1[nt] = c1;
        }
        // p = exp2(s); pack bf16 B-frags; denominators via ones-MFMA
        short4v pf0[4], pf1[4];
        #pragma unroll
        for (int nt = 0; nt < 4; nt++) {
            {
                float p0 = __builtin_amdgcn_exp2f(s0[nt][0]);
                float p1 = __builtin_amdgcn_exp2f(s0[nt][1]);
                float p2 = __builtin_amdgcn_exp2f(s0[nt][2]);
                float p3 = __builtin_amdgcn_exp2f(s0[nt][3]);
                uint2 pk;
                pk.x = __builtin_amdgcn_perm(__float_as_uint(p1), __float_as_uint(p0), 0x07060302);
                pk.y = __builtin_amdgcn_perm(__float_as_uint(p3), __float_as_uint(p2), 0x07060302);
                union { uint2 u; short4v s4; } cv; cv.u = pk;
                pf0[nt] = cv.s4;
                l_acc[0] = mfma16k16(ones, pf0[nt], l_acc[0]);
            }
            {
                float p0 = __builtin_amdgcn_exp2f(s1[nt][0]);
                float p1 = __builtin_amdgcn_exp2f(s1[nt][1]);
                float p2 = __builtin_amdgcn_exp2f(s1[nt][2]);
                float p3 = __builtin_amdgcn_exp2f(s1[nt][3]);
                uint2 pk;
                pk.x = __builtin_amdgcn_perm(__float_as_uint(p1), __float_as_uint(p0), 0x07060302);
                pk.y = __builtin_amdgcn_perm(__float_as_uint(p3), __float_as_uint(p2), 0x07060302);
                union { uint2 u; short4v s4; } cv; cv.u = pk;
                pf1[nt] = cv.s4;
                l_acc[1] = mfma16k16(ones, pf1[nt], l_acc[1]);
            }
        }
        // O^T += V^T * P — V-frags read once, used by both q-tiles
        #pragma unroll
        for (int dt = 0; dt < 4; dt++) {
            const unsigned short* vp = lds_v + (dt * 16 + lrow) * PAD + lq * 16;
            short8v v01 = *(const short8v*)vp;
            short8v v23 = *(const short8v*)(vp + 8);
            short4v va = __builtin_shufflevector(v01, v01, 0, 1, 2, 3);
            short4v vb = __builtin_shufflevector(v01, v01, 4, 5, 6, 7);
            short4v vc = __builtin_shufflevector(v23, v23, 0, 1, 2, 3);
            short4v vd = __builtin_shufflevector(v23, v23, 4, 5, 6, 7);
            o_acc[0][dt] = mfma16k16(va, pf0[0], o_acc[0][dt]);
            o_acc[0][dt] = mfma16k16(vb, pf0[1], o_acc[0][dt]);
            o_acc[0][dt] = mfma16k16(vc, pf0[2], o_acc[0][dt]);
            o_acc[0][dt] = mfma16k16(vd, pf0[3], o_acc[0][dt]);
            o_acc[1][dt] = mfma16k16(va, pf1[0], o_acc[1][dt]);
            o_acc[1][dt] = mfma16k16(vb, pf1[1], o_acc[1][dt]);
            o_acc[1][dt] = mfma16k16(vc, pf1[2], o_acc[1][dt]);
            o_acc[1][dt] = mfma16k16(vd, pf1[3], o_acc[1][dt]);
        }
    }
    int h = bh & 15, b = bh >> 4;
    #pragma unroll
    for (int qt = 0; qt < 2; qt++) {
        float rl = 1.0f / l_acc[qt][0];
        int i = i0 + w * 32 + qt * 16 + lrow;
        unsigned short* orow = att + ((long)(b * T_SEQ + i)) * D_MODEL + h * 64;
        #pragma unroll
        for (int dt = 0; dt < 4; dt++) {
            uint2 o;
            o.x = pack2_bf16(o_acc[qt][dt][0] * rl, o_acc[qt][dt][1] * rl);
            o.y = pack2_bf16(o_acc[qt][dt][2] * rl, o_acc[qt][dt][3] * rl);
            *(uint2*)(orow + dt * 16 + lq * 4) = o;
        }
    }
}

// ---------------- LayerNorm in-place on d_out ----------------
__global__ __launch_bounds__(256) void k_ln(float* __restrict__ io,
                                            const float* __restrict__ gamma,
                                            const float* __restrict__ beta) {
    int row = blockIdx.x, t = threadIdx.x;
    float* p = io + (long)row * D_MODEL + t * 4;
    float4 v = *(float4*)p;
    float s = v.x + v.y + v.z + v.w;
    float ss = v.x * v.x + v.y * v.y + v.z * v.z + v.w * v.w;
    #pragma unroll
    for (int m = 1; m < 64; m <<= 1) {
        s += __shfl_xor(s, m);
        ss += __shfl_xor(ss, m);
    }
    __shared__ float red[8];
    if ((t & 63) == 0) { red[t >> 6] = s; red[4 + (t >> 6)] = ss; }
    __syncthreads();
    s = red[0] + red[1] + red[2] + red[3];
    ss = red[4] + red[5] + red[6] + red[7];
    float mu = s * (1.0f / 1024.0f);
    float var = ss * (1.0f / 1024.0f) - mu * mu;
    float rstd = rsqrtf(var + 1e-5f);
    float4 g = *(const float4*)(gamma + t * 4);
    float4 be = *(const float4*)(beta + t * 4);
    float4 o;
    o.x = (v.x - mu) * rstd * g.x + be.x;
    o.y = (v.y - mu) * rstd * g.y + be.y;
    o.z = (v.z - mu) * rstd * g.z + be.z;
    o.w = (v.w - mu) * rstd * g.w + be.w;
    *(float4*)p = o;
}

extern "C" void kernel_launch(void* const* d_in, const int* in_sizes, int n_in,
                              void* d_out, int out_size, void* d_ws, size_t ws_size,
                              hipStream_t stream) {
    const float* x = (const float*)d_in[0];
    const float* Wq = (const float*)d_in[1];
    const float* bq = (const float*)d_in[2];
    const float* Wk = (const float*)d_in[3];
    const float* bk = (const float*)d_in[4];
    const float* Wv = (const float*)d_in[5];
    const float* bv = (const float*)d_in[6];
    const float* Wo = (const float*)d_in[7];
    const float* bo = (const float*)d_in[8];
    const float* gamma = (const float*)d_in[9];
    const float* beta = (const float*)d_in[10];
    float* out = (float*)d_out;

    char* ws = (char*)d_ws;
    unsigned short* x_bf = (unsigned short*)(ws);                       // 8 MB (reused as att)
    unsigned short* wqkv_bf = (unsigned short*)(ws + ((size_t)8 << 20));// 6 MB
    unsigned short* wo_bf = (unsigned short*)(ws + ((size_t)14 << 20)); // 2 MB
    unsigned short* qkv_ws = (unsigned short*)(ws + ((size_t)16 << 20));// 24 MB (q|k|vt)
    unsigned short* att = x_bf;  // alias: x_bf dead after QKV GEMM

    unsigned short* q_ws = qkv_ws;
    unsigned short* k_ws = qkv_ws + (size_t)32 * T_SEQ * DH;
    unsigned short* vtg = qkv_ws + (size_t)64 * T_SEQ * DH;

    k_conv_all<<<8192, 256, 0, stream>>>(x, Wq, Wk, Wv, Wo, x_bf, wqkv_bf, wo_bf);

    // fused QKV GEMM: N = 3072, 1D grid with XCD swizzle
    k_gemm<128, 0><<<768, 256, 0, stream>>>(
        x_bf, wqkv_bf, bq, bk, bv, nullptr, qkv_ws, vtg, nullptr);

    k_attn<<<512, 256, 0, stream>>>(q_ws, k_ws, vtg, att);

    // O-projection + bias + residual: N = 1024, 1D grid with XCD swizzle
    k_gemm<64, 1><<<512, 256, 0, stream>>>(
        att, wo_bf, bo, nullptr, nullptr, x, nullptr, nullptr, out);

    k_ln<<<NROWS, 256, 0, stream>>>(out, gamma, beta);
}

// Round 6
// 215.623 us; speedup vs baseline: 1.7255x; 1.0147x over previous
//
#include <hip/hip_runtime.h>
#include <stdint.h>

#define T_SEQ 2048
#define D_MODEL 1024
#define NH 16
#define DH 64
#define NROWS 4096  // B*T

typedef __bf16 bf16x8 __attribute__((ext_vector_type(8)));
typedef float floatx4 __attribute__((ext_vector_type(4)));
typedef short short4v __attribute__((ext_vector_type(4)));
typedef short short8v __attribute__((ext_vector_type(8)));

#define AS1 __attribute__((address_space(1)))
#define AS3 __attribute__((address_space(3)))

static __device__ __forceinline__ void gl2lds16(const unsigned short* g, unsigned short* s) {
    __builtin_amdgcn_global_load_lds((const AS1 unsigned int*)g, (AS3 unsigned int*)s, 16, 0, 0);
}

static __device__ __forceinline__ unsigned short f32_bf16(float f) {
    union { float f; unsigned int u; } c; c.f = f;
    unsigned int u = c.u;
    u = u + 0x7FFFu + ((u >> 16) & 1u);   // RNE
    return (unsigned short)(u >> 16);
}

static __device__ __forceinline__ unsigned int pack2_bf16(float a, float b) {
    return (unsigned int)f32_bf16(a) | ((unsigned int)f32_bf16(b) << 16);
}

static __device__ __forceinline__ floatx4 mfma16(bf16x8 a, bf16x8 b, floatx4 c) {
    return __builtin_amdgcn_mfma_f32_16x16x32_bf16(a, b, c, 0, 0, 0);
}

static __device__ __forceinline__ floatx4 mfma16k16(short4v a, short4v b, floatx4 c) {
#if defined(__HIP_DEVICE_COMPILE__)
    return __builtin_amdgcn_mfma_f32_16x16x16bf16_1k(a, b, c, 0, 0, 0);
#else
    (void)a; (void)b;
    return c;  // host stub — never executed
#endif
}

#define QSCALE 0.1803368801111204f   // (1/8) * log2(e); softmax in exp2 domain
#define EXP2_SHIFT 10.0f
// s_waitcnt imm: vmcnt[3:0]|[15:14], expcnt[6:4]=7 (nowait), lgkmcnt[11:8]=0xF (nowait)
#define WAITCNT_VM4 0x0F74
#define WAITCNT_VM0 0x0F70

// ---------------- fused conversion kernel ----------------
// blocks 0..4095: x fp32->bf16; 4096..7167: Wq/Wk/Wv row-permute; 7168..8191: Wo col-permute
__global__ __launch_bounds__(256) void k_conv_all(const float* __restrict__ x,
                                                  const float* __restrict__ Wq,
                                                  const float* __restrict__ Wk,
                                                  const float* __restrict__ Wv,
                                                  const float* __restrict__ Wo,
                                                  unsigned short* __restrict__ x_bf,
                                                  unsigned short* __restrict__ wqkv_bf,
                                                  unsigned short* __restrict__ wo_bf) {
    int b = blockIdx.x, t = threadIdx.x;
    if (b < 4096) {
        int i = b * 1024 + t * 4;
        float4 v = *(const float4*)(x + i);
        uint2 o;
        o.x = pack2_bf16(v.x, v.y);
        o.y = pack2_bf16(v.z, v.w);
        *(uint2*)(x_bf + i) = o;
    } else if (b < 7168) {
        int idx = b - 4096;
        int tensor = idx >> 10, np = idx & 1023;
        const float* src = tensor == 0 ? Wq : tensor == 1 ? Wk : Wv;
        int f = (np & 63) * 16 + (np >> 6);
        int c = t * 4;
        float4 v = *(const float4*)(src + (long)f * D_MODEL + c);
        uint2 o;
        o.x = pack2_bf16(v.x, v.y);
        o.y = pack2_bf16(v.z, v.w);
        *(uint2*)(wqkv_bf + ((long)tensor * D_MODEL + np) * D_MODEL + c) = o;
    } else {
        int n = b - 7168;
        int fp = t * 4;
        const float* row = Wo + (long)n * D_MODEL;
        unsigned short o[4];
        #pragma unroll
        for (int k = 0; k < 4; k++) {
            int f = fp + k;
            o[k] = f32_bf16(row[(f & 63) * 16 + (f >> 6)]);
        }
        *(uint2*)(wo_bf + (long)n * D_MODEL + fp) = *(const uint2*)o;
    }
}

// ---------------- GEMM: C = A(bf16) @ W(bf16)^T, K = 1024 ----------------
// BM=128, BK=64, 256 threads = 4 waves 2x2; XOR-swizzled LDS (conflict-free frag reads
// while keeping global_load_lds lane-order); XCD-aware 1D block swizzle.
// MODE 0: fused QKV (W stacked 3072x1024); grid 768. MODE 1: O-proj; grid 512.
template <int BN, int MODE>
__global__ __launch_bounds__(256) void k_gemm(const unsigned short* __restrict__ A,
                                              const unsigned short* __restrict__ W,
                                              const float* __restrict__ b0,
                                              const float* __restrict__ b1,
                                              const float* __restrict__ b2,
                                              const float* __restrict__ resid,
                                              unsigned short* __restrict__ out_bf,
                                              unsigned short* __restrict__ vtg,
                                              float* __restrict__ out_f32) {
    constexpr int NT = BN / 32;
    constexpr int NCB = BN / 32;
    __shared__ unsigned short lds_a[128 * 64];
    __shared__ unsigned short lds_b[BN * 64];
    const int tid = threadIdx.x;
    const int w = tid >> 6, l = tid & 63;
    const int lrow = l & 15, lq = l >> 4;
    const int wm = (w >> 1) * 64, wn = (w & 1) * (BN / 2);
    // XCD swizzle: same x-tile stays on one XCD (assumes xcd = linearID % 8)
    const int L = blockIdx.x;
    const int bx = (L & 7) * 4 + ((L >> 3) & 3);
    const int by = L >> 5;
    const long am0 = (long)bx * 128;
    const long wn0 = (long)by * BN;

    floatx4 acc[4][NT] = {};
    const int grow = l >> 3;
    const int gcol = ((l & 7) ^ grow) * 8;    // column-group XOR swizzle on the global side
    const int sw8 = (lrow & 7);

    for (int k0 = 0; k0 < D_MODEL; k0 += 64) {
        #pragma unroll
        for (int c = 0; c < 4; c++) {
            int chunk = w * 4 + c;
            gl2lds16(A + (am0 + chunk * 8 + grow) * D_MODEL + k0 + gcol,
                     lds_a + chunk * 512);
        }
        #pragma unroll
        for (int c = 0; c < NCB; c++) {
            int chunk = w * NCB + c;
            gl2lds16(W + (wn0 + chunk * 8 + grow) * D_MODEL + k0 + gcol,
                     lds_b + chunk * 512);
        }
        __syncthreads();

        bf16x8 af[4][2], bf[NT][2];
        #pragma unroll
        for (int mt = 0; mt < 4; mt++)
            #pragma unroll
            for (int ks = 0; ks < 2; ks++)
                af[mt][ks] = *(const bf16x8*)(lds_a + (wm + mt * 16 + lrow) * 64 +
                                              (((ks * 4 + lq) ^ sw8) * 8));
        #pragma unroll
        for (int nt = 0; nt < NT; nt++)
            #pragma unroll
            for (int ks = 0; ks < 2; ks++)
                bf[nt][ks] = *(const bf16x8*)(lds_b + (wn + nt * 16 + lrow) * 64 +
                                              (((ks * 4 + lq) ^ sw8) * 8));
        #pragma unroll
        for (int mt = 0; mt < 4; mt++)
            #pragma unroll
            for (int nt = 0; nt < NT; nt++)
                #pragma unroll
                for (int ks = 0; ks < 2; ks++)
                    acc[mt][nt] = mfma16(af[mt][ks], bf[nt][ks], acc[mt][nt]);
        __syncthreads();
    }

    if (MODE == 0) {
        int tensor = by >> 3;                    // 0=Q 1=K 2=V
        int nbase = (by & 7) * 128;
        const float* bias = tensor == 0 ? b0 : tensor == 1 ? b1 : b2;
        float scale = tensor == 0 ? QSCALE : 1.0f;
        if (tensor < 2) {
            unsigned short* outt = out_bf + (size_t)tensor * (32u * T_SEQ * DH);
            #pragma unroll
            for (int mt = 0; mt < 4; mt++) {
                #pragma unroll
                for (int nt = 0; nt < NT; nt++) {
                    int n = nbase + wn + nt * 16 + lrow;     // n' = h*64+d
                    int h = n >> 6, d = n & 63;
                    float bb = bias[d * 16 + h];
                    #pragma unroll
                    for (int r = 0; r < 4; r++) {
                        int row = (int)am0 + wm + mt * 16 + lq * 4 + r;
                        float v = (acc[mt][nt][r] + bb) * scale;
                        int b = row >> 11, i = row & 2047;
                        long idx = ((long)(b * 16 + h) * T_SEQ + i) * DH + d;
                        outt[idx] = f32_bf16(v);
                    }
                }
            }
        } else {
            // V -> vtg[((bh*64+d)*32 + blk)*64 + j'], j' = lq*16 + mt*4 + r
            int row0 = (int)am0 + wm;                    // multiple of 64
            int b = row0 >> 11;
            int blk = (row0 & 2047) >> 6;
            #pragma unroll
            for (int nt = 0; nt < NT; nt++) {
                int n = nbase + wn + nt * 16 + lrow;
                int h = n >> 6, d = n & 63;
                float bb = bias[d * 16 + h];
                long base = (((long)(b * 16 + h) * 64 + d) * 32 + blk) * 64;
                #pragma unroll
                for (int mt = 0; mt < 4; mt++) {
                    uint2 o;
                    o.x = pack2_bf16(acc[mt][nt][0] + bb, acc[mt][nt][1] + bb);
                    o.y = pack2_bf16(acc[mt][nt][2] + bb, acc[mt][nt][3] + bb);
                    *(uint2*)(vtg + base + lq * 16 + mt * 4) = o;
                }
            }
        }
    } else {
        #pragma unroll
        for (int mt = 0; mt < 4; mt++) {
            #pragma unroll
            for (int nt = 0; nt < NT; nt++) {
                int n = (int)wn0 + wn + nt * 16 + lrow;
                float bb = b0[n];
                #pragma unroll
                for (int r = 0; r < 4; r++) {
                    int row = (int)am0 + wm + mt * 16 + lq * 4 + r;
                    long idx = (long)row * D_MODEL + n;
                    out_f32[idx] = acc[mt][nt][r] + bb + resid[idx];
                }
            }
        }
    }
}

// ---------------- attention: S^T trick + async double-buffered K/V pipeline --------
// Block = 128 q-rows (2 q-tiles/wave); K/V staged by global_load_lds into 2 LDS bufs.
// Granule XOR swizzle on the GLOBAL address side: lane l loads granule (l&7)^((l>>3)&7),
// so LDS(row r, pos p) = G(row r, granule p^(r&7)); frag reads are single 16-B granules
// at pos g^(r&7) -> all 8 bank-groups covered -> conflict-free, no padding.
// Top-of-loop: raw s_barrier + manual s_waitcnt vmcnt(4) keeps next-tile DMA in flight.
__global__ __launch_bounds__(256) void k_attn(const unsigned short* __restrict__ q_ws,
                                              const unsigned short* __restrict__ k_ws,
                                              const unsigned short* __restrict__ vtg,
                                              unsigned short* __restrict__ att) {
    __shared__ unsigned short kbuf[2 * 64 * 64];
    __shared__ unsigned short vbuf[2 * 64 * 64];
    const int tid = threadIdx.x;
    const int w = tid >> 6, l = tid & 63;
    const int lrow = l & 15, lq = l >> 4;
    const int sw = lrow & 7;
    const int L = blockIdx.x;
    const int bh = (L & 7) * 4 + ((L >> 3) & 3);   // 4 bh per XCD -> K/V L2-resident
    const int i0 = (L >> 5) * 128;
    const unsigned short* kh = k_ws + (long)bh * T_SEQ * DH;
    const unsigned short* vh = vtg + (long)bh * 64 * T_SEQ;  // [d][blk][j']

    const int rl = l >> 3;                     // staging: row within 8-row chunk
    const int gl = ((l & 7) ^ rl) * 8;         // staging: swizzled granule (shorts)

    bf16x8 qf[2][2];
    #pragma unroll
    for (int qt = 0; qt < 2; qt++) {
        const unsigned short* qp =
            q_ws + ((long)bh * T_SEQ + i0 + w * 32 + qt * 16 + lrow) * DH + lq * 8;
        qf[qt][0] = *(const bf16x8*)qp;
        qf[qt][1] = *(const bf16x8*)(qp + 32);
    }
    floatx4 o_acc[2][4] = {};
    floatx4 l_acc[2] = {};
    const short4v ones = {0x3F80, 0x3F80, 0x3F80, 0x3F80};

    // stage tile jt into buffer sel (4 global_load_lds per thread: 2 K + 2 V)
    auto stage = [&](int jt, int sel) {
        unsigned short* kd = kbuf + sel * 4096 + (w * 2) * 512;
        unsigned short* vd = vbuf + sel * 4096 + (w * 2) * 512;
        #pragma unroll
        for (int c = 0; c < 2; c++) {
            int row = w * 16 + c * 8 + rl;     // 0..63
            gl2lds16(kh + ((long)(jt * 64 + row)) * 64 + gl, kd + c * 512);
            gl2lds16(vh + ((long)row * 32 + jt) * 64 + gl, vd + c * 512);
        }
    };

    stage(0, 0);

    for (int jt = 0; jt < T_SEQ / 64; jt++) {
        const int cur = jt & 1;
        if (jt < T_SEQ / 64 - 1) {
            stage(jt + 1, 1 - cur);
            __builtin_amdgcn_s_waitcnt(WAITCNT_VM4);   // drain prev tile, keep prefetch
        } else {
            __builtin_amdgcn_s_waitcnt(WAITCNT_VM0);
        }
        __builtin_amdgcn_s_barrier();

        const unsigned short* kb_ = kbuf + cur * 4096;
        const unsigned short* vb_ = vbuf + cur * 4096;

        // S^T - 10 for both q-tiles; K-frags read once (single-granule b128s)
        floatx4 s0[4], s1[4];
        #pragma unroll
        for (int nt = 0; nt < 4; nt++) {
            const unsigned short* kp = kb_ + (nt * 16 + lrow) * 64;
            bf16x8 ka = *(const bf16x8*)(kp + ((lq ^ sw) * 8));
            bf16x8 kb = *(const bf16x8*)(kp + (((lq + 4) ^ sw) * 8));
            floatx4 c0 = {-EXP2_SHIFT, -EXP2_SHIFT, -EXP2_SHIFT, -EXP2_SHIFT};
            floatx4 c1 = c0;
            c0 = mfma16(ka, qf[0][0], c0);
            c0 = mfma16(kb, qf[0][1], c0);
            c1 = mfma16(ka, qf[1][0], c1);
            c1 = mfma16(kb, qf[1][1], c1);
            s0[nt] = c0;
            s1[nt] = c1;
        }
        // p = exp2(s); pack bf16 B-frags; denominators via ones-MFMA
        short4v pf0[4], pf1[4];
        #pragma unroll
        for (int nt = 0; nt < 4; nt++) {
            {
                float p0 = __builtin_amdgcn_exp2f(s0[nt][0]);
                float p1 = __builtin_amdgcn_exp2f(s0[nt][1]);
                float p2 = __builtin_amdgcn_exp2f(s0[nt][2]);
                float p3 = __builtin_amdgcn_exp2f(s0[nt][3]);
                uint2 pk;
                pk.x = __builtin_amdgcn_perm(__float_as_uint(p1), __float_as_uint(p0), 0x07060302);
                pk.y = __builtin_amdgcn_perm(__float_as_uint(p3), __float_as_uint(p2), 0x07060302);
                union { uint2 u; short4v s4; } cv; cv.u = pk;
                pf0[nt] = cv.s4;
                l_acc[0] = mfma16k16(ones, pf0[nt], l_acc[0]);
            }
            {
                float p0 = __builtin_amdgcn_exp2f(s1[nt][0]);
                float p1 = __builtin_amdgcn_exp2f(s1[nt][1]);
                float p2 = __builtin_amdgcn_exp2f(s1[nt][2]);
                float p3 = __builtin_amdgcn_exp2f(s1[nt][3]);
                uint2 pk;
                pk.x = __builtin_amdgcn_perm(__float_as_uint(p1), __float_as_uint(p0), 0x07060302);
                pk.y = __builtin_amdgcn_perm(__float_as_uint(p3), __float_as_uint(p2), 0x07060302);
                union { uint2 u; short4v s4; } cv; cv.u = pk;
                pf1[nt] = cv.s4;
                l_acc[1] = mfma16k16(ones, pf1[nt], l_acc[1]);
            }
        }
        // O^T += V^T * P — V-frags read once (single-granule reads), both q-tiles
        #pragma unroll
        for (int dt = 0; dt < 4; dt++) {
            const unsigned short* vp = vb_ + (dt * 16 + lrow) * 64;
            short8v v01 = *(const short8v*)(vp + (((2 * lq) ^ sw) * 8));
            short8v v23 = *(const short8v*)(vp + (((2 * lq + 1) ^ sw) * 8));
            short4v va = __builtin_shufflevector(v01, v01, 0, 1, 2, 3);
            short4v vb = __builtin_shufflevector(v01, v01, 4, 5, 6, 7);
            short4v vc = __builtin_shufflevector(v23, v23, 0, 1, 2, 3);
            short4v vd = __builtin_shufflevector(v23, v23, 4, 5, 6, 7);
            o_acc[0][dt] = mfma16k16(va, pf0[0], o_acc[0][dt]);
            o_acc[0][dt] = mfma16k16(vb, pf0[1], o_acc[0][dt]);
            o_acc[0][dt] = mfma16k16(vc, pf0[2], o_acc[0][dt]);
            o_acc[0][dt] = mfma16k16(vd, pf0[3], o_acc[0][dt]);
            o_acc[1][dt] = mfma16k16(va, pf1[0], o_acc[1][dt]);
            o_acc[1][dt] = mfma16k16(vb, pf1[1], o_acc[1][dt]);
            o_acc[1][dt] = mfma16k16(vc, pf1[2], o_acc[1][dt]);
            o_acc[1][dt] = mfma16k16(vd, pf1[3], o_acc[1][dt]);
        }
        __syncthreads();   // all reads of buf[cur] done before it is re-staged
    }
    int h = bh & 15, b = bh >> 4;
    #pragma unroll
    for (int qt = 0; qt < 2; qt++) {
        float rl2 = 1.0f / l_acc[qt][0];
        int i = i0 + w * 32 + qt * 16 + lrow;
        unsigned short* orow = att + ((long)(b * T_SEQ + i)) * D_MODEL + h * 64;
        #pragma unroll
        for (int dt = 0; dt < 4; dt++) {
            uint2 o;
            o.x = pack2_bf16(o_acc[qt][dt][0] * rl2, o_acc[qt][dt][1] * rl2);
            o.y = pack2_bf16(o_acc[qt][dt][2] * rl2, o_acc[qt][dt][3] * rl2);
            *(uint2*)(orow + dt * 16 + lq * 4) = o;
        }
    }
}

// ---------------- LayerNorm in-place on d_out ----------------
__global__ __launch_bounds__(256) void k_ln(float* __restrict__ io,
                                            const float* __restrict__ gamma,
                                            const float* __restrict__ beta) {
    int row = blockIdx.x, t = threadIdx.x;
    float* p = io + (long)row * D_MODEL + t * 4;
    float4 v = *(float4*)p;
    float s = v.x + v.y + v.z + v.w;
    float ss = v.x * v.x + v.y * v.y + v.z * v.z + v.w * v.w;
    #pragma unroll
    for (int m = 1; m < 64; m <<= 1) {
        s += __shfl_xor(s, m);
        ss += __shfl_xor(ss, m);
    }
    __shared__ float red[8];
    if ((t & 63) == 0) { red[t >> 6] = s; red[4 + (t >> 6)] = ss; }
    __syncthreads();
    s = red[0] + red[1] + red[2] + red[3];
    ss = red[4] + red[5] + red[6] + red[7];
    float mu = s * (1.0f / 1024.0f);
    float var = ss * (1.0f / 1024.0f) - mu * mu;
    float rstd = rsqrtf(var + 1e-5f);
    float4 g = *(const float4*)(gamma + t * 4);
    float4 be = *(const float4*)(beta + t * 4);
    float4 o;
    o.x = (v.x - mu) * rstd * g.x + be.x;
    o.y = (v.y - mu) * rstd * g.y + be.y;
    o.z = (v.z - mu) * rstd * g.z + be.z;
    o.w = (v.w - mu) * rstd * g.w + be.w;
    *(float4*)p = o;
}

extern "C" void kernel_launch(void* const* d_in, const int* in_sizes, int n_in,
                              void* d_out, int out_size, void* d_ws, size_t ws_size,
                              hipStream_t stream) {
    const float* x = (const float*)d_in[0];
    const float* Wq = (const float*)d_in[1];
    const float* bq = (const float*)d_in[2];
    const float* Wk = (const float*)d_in[3];
    const float* bk = (const float*)d_in[4];
    const float* Wv = (const float*)d_in[5];
    const float* bv = (const float*)d_in[6];
    const float* Wo = (const float*)d_in[7];
    const float* bo = (const float*)d_in[8];
    const float* gamma = (const float*)d_in[9];
    const float* beta = (const float*)d_in[10];
    float* out = (float*)d_out;

    char* ws = (char*)d_ws;
    unsigned short* x_bf = (unsigned short*)(ws);                       // 8 MB (reused as att)
    unsigned short* wqkv_bf = (unsigned short*)(ws + ((size_t)8 << 20));// 6 MB
    unsigned short* wo_bf = (unsigned short*)(ws + ((size_t)14 << 20)); // 2 MB
    unsigned short* qkv_ws = (unsigned short*)(ws + ((size_t)16 << 20));// 24 MB (q|k|vt)
    unsigned short* att = x_bf;  // alias: x_bf dead after QKV GEMM

    unsigned short* q_ws = qkv_ws;
    unsigned short* k_ws = qkv_ws + (size_t)32 * T_SEQ * DH;
    unsigned short* vtg = qkv_ws + (size_t)64 * T_SEQ * DH;

    k_conv_all<<<8192, 256, 0, stream>>>(x, Wq, Wk, Wv, Wo, x_bf, wqkv_bf, wo_bf);

    // fused QKV GEMM: N = 3072, 1D grid with XCD swizzle
    k_gemm<128, 0><<<768, 256, 0, stream>>>(
        x_bf, wqkv_bf, bq, bk, bv, nullptr, qkv_ws, vtg, nullptr);

    k_attn<<<512, 256, 0, stream>>>(q_ws, k_ws, vtg, att);

    // O-projection + bias + residual: N = 1024, 1D grid with XCD swizzle
    k_gemm<64, 1><<<512, 256, 0, stream>>>(
        att, wo_bf, bo, nullptr, nullptr, x, nullptr, nullptr, out);

    k_ln<<<NROWS, 256, 0, stream>>>(out, gamma, beta);
}